// Round 9
// baseline (1211.059 us; speedup 1.0000x reference)
//
#include <hip/hip_runtime.h>
#include <hip/hip_bf16.h>

#define N_NODES 50000
#define N_EDGES 800000
#define HID 64
#define N_GRAPHS 64
#define N_CLASSES 10
#define BN_EPS 1e-5f
#define NBKT 782           // ceil(50000/64)
#define FILL_BLOCKS 128

typedef unsigned int uint;
typedef unsigned short ushort;

__device__ __forceinline__ float blo(uint u) { return __uint_as_float(u << 16); }
__device__ __forceinline__ float bhi(uint u) { return __uint_as_float(u & 0xffff0000u); }
__device__ __forceinline__ unsigned short f2b(float f) {
  __hip_bfloat16 h = __float2bfloat16(f);
  return *reinterpret_cast<unsigned short*>(&h);
}

// ---------------- build ----------------

__global__ void k_count_deg(const int* __restrict__ dst, int* __restrict__ deg) {
  int e = blockIdx.x * blockDim.x + threadIdx.x;
  if (e < N_EDGES) atomicAdd(&deg[__builtin_nontemporal_load(&dst[e])], 1);
}

// dis[i] = rsqrt(deg+1); bucket sums of deg via wave-reduce (1 wave = 1 bucket)
__global__ void k_dis_bkt(const int* __restrict__ deg, float* __restrict__ dis,
                          int* __restrict__ bktsum) {
  int i = blockIdx.x * 256 + threadIdx.x;
  int v = (i < N_NODES) ? deg[i] : 0;
  if (i < N_NODES) dis[i] = rsqrtf((float)v + 1.0f);
  int s = v;
#pragma unroll
  for (int off = 1; off < 64; off <<= 1) s += __shfl_xor(s, off, 64);
  if ((threadIdx.x & 63) == 0) {
    int b = i >> 6;
    if (b < NBKT) bktsum[b] = s;
  }
}

// single-block exclusive scan over NBKT bucket sums -> bro (ranges) + bcur (cursors)
__global__ void k_scan_bkt(const int* __restrict__ bktsum, int* __restrict__ bro,
                           int* __restrict__ bcur) {
  __shared__ int s[256];
  int tid = threadIdx.x;
  int loc[4];
  int sum = 0;
#pragma unroll
  for (int k = 0; k < 4; ++k) {
    int b = tid * 4 + k;
    loc[k] = sum;
    sum += (b < NBKT) ? bktsum[b] : 0;
  }
  s[tid] = sum;
  __syncthreads();
  for (int off = 1; off < 256; off <<= 1) {
    int t = (tid >= off) ? s[tid - off] : 0;
    __syncthreads();
    s[tid] += t;
    __syncthreads();
  }
  int excl = s[tid] - sum;
#pragma unroll
  for (int k = 0; k < 4; ++k) {
    int b = tid * 4 + k;
    if (b < NBKT) {
      bro[b] = excl + loc[k];
      bcur[b] = excl + loc[k];
    }
  }
  if (tid == 0) bro[NBKT] = N_EDGES;
}

// two-phase counting sort into 64-node buckets; rec = src<<6 | (dst&63)
__global__ __launch_bounds__(256) void k_fill(const int* __restrict__ ei,
                                              int* __restrict__ bcur,
                                              uint* __restrict__ edata) {
  __shared__ int lcnt[NBKT];
  __shared__ int lbase[NBKT];
  int tid = threadIdx.x;
  const int per = (N_EDGES + FILL_BLOCKS - 1) / FILL_BLOCKS;  // 6250
  int c0 = blockIdx.x * per;
  int c1 = c0 + per;
  if (c1 > N_EDGES) c1 = N_EDGES;
  for (int i = tid; i < NBKT; i += 256) lcnt[i] = 0;
  __syncthreads();
  for (int e = c0 + tid; e < c1; e += 256) {
    int d = __builtin_nontemporal_load(&ei[N_EDGES + e]);
    atomicAdd(&lcnt[d >> 6], 1);
  }
  __syncthreads();
  for (int b = tid; b < NBKT; b += 256) lbase[b] = atomicAdd(&bcur[b], lcnt[b]);
  __syncthreads();
  for (int e = c0 + tid; e < c1; e += 256) {
    int sct = __builtin_nontemporal_load(&ei[e]);
    int d = __builtin_nontemporal_load(&ei[N_EDGES + e]);
    int pos = atomicAdd(&lbase[d >> 6], 1);
    edata[pos] = ((uint)sct << 6) | (uint)(d & 63);  // plain store: L2 merges
  }
}

// ---------------- per-layer ----------------

// out16[n][j] = bf16( sum_k bnrelu(in[n][k]) * W[k][j] )
template <bool IN_BF16>
__global__ __launch_bounds__(256) void k_gemm(const void* __restrict__ in,
                                              const float* __restrict__ W,
                                              __hip_bfloat16* __restrict__ out,
                                              float* __restrict__ stats_zero,
                                              const float* __restrict__ stats_in,
                                              const float* __restrict__ gamma,
                                              const float* __restrict__ beta) {
  __shared__ float Al[4][64];
  int tid = threadIdx.x;
  int wid = tid >> 6, f = tid & 63;
  if (blockIdx.x == 0) {
    for (int i = tid; i < 1024; i += 256) stats_zero[i] = 0.0f;
  }
  float Wreg[64];
#pragma unroll
  for (int k = 0; k < 64; ++k) Wreg[k] = W[k * 64 + f];
  float sc = 1.f, sh = 0.f;
  if (stats_in) {
    float s = 0.f, q = 0.f;
#pragma unroll
    for (int c = 0; c < 8; ++c) {
      s += stats_in[c * 128 + f];
      q += stats_in[c * 128 + 64 + f];
    }
    float mu = s * (1.0f / N_NODES);
    float var = q * (1.0f / N_NODES) - mu * mu;
    sc = gamma[f] * rsqrtf(var + BN_EPS);
    sh = beta[f] - mu * sc;
  }
  for (int n = blockIdx.x * 4 + wid; n < N_NODES; n += gridDim.x * 4) {
    float av;
    if (IN_BF16) {
      ushort u = ((const ushort*)in)[(n << 6) + f];
      av = __uint_as_float((uint)u << 16);
    } else {
      av = ((const float*)in)[(n << 6) + f];
    }
    if (stats_in) {
      av = fmaf(av, sc, sh);
      av = av > 0.f ? av : 0.f;
    }
    Al[wid][f] = av;  // same-wave LDS: ordered, no barrier
    float acc = 0.f;
    const float4* arow = (const float4*)Al[wid];
#pragma unroll
    for (int k4 = 0; k4 < 16; ++k4) {
      float4 a = arow[k4];
      acc = fmaf(a.x, Wreg[k4 * 4 + 0], acc);
      acc = fmaf(a.y, Wreg[k4 * 4 + 1], acc);
      acc = fmaf(a.z, Wreg[k4 * 4 + 2], acc);
      acc = fmaf(a.w, Wreg[k4 * 4 + 3], acc);
    }
    out[(n << 6) + f] = __float2bfloat16(acc);  // cached: gather target
  }
}

// Bucketed LDS-accumulate aggregation: 1 block = 64 dst nodes.
// Edge stream: per 8 edges -> 8 independent row gathers + LDS float atomics.
// No per-node chain, no shuffle reduce. dis[dst] factored into epilogue.
__global__ __launch_bounds__(256, 4) void k_agg_bkt(
    const __hip_bfloat16* __restrict__ hW, const float* __restrict__ dis,
    const int* __restrict__ bro, const uint* __restrict__ edata,
    const float* __restrict__ bias, __hip_bfloat16* __restrict__ act,
    float* __restrict__ stats) {
  __shared__ float accL[64 * 65];  // stride 65: spreads banks across dst rows
  __shared__ float ssum[4][64], ssq[4][64];
  int tid = threadIdx.x;
  int wid = tid >> 6, lane = tid & 63;
  int g = lane >> 3, l8 = lane & 7;
  int b = blockIdx.x;
  for (int i = tid; i < 64 * 65; i += 256) accL[i] = 0.f;
  int e0 = bro[b], e1 = bro[b + 1];
  __syncthreads();
  const uint4* hw4 = (const uint4*)hW;
  for (int p = e0 + wid * 64; p < e1; p += 256) {
    int vcnt = e1 - p;
    if (vcnt > 64) vcnt = 64;
    uint rec = (p + lane < e1) ? edata[p + lane] : 0u;
#pragma unroll
    for (int sb = 0; sb < 8; ++sb) {
      if (sb * 8 >= vcnt) break;
      bool v = (sb * 8 + g) < vcnt;
      uint e = __shfl(rec, sb * 8 + g, 64);
      uint src = v ? (e >> 6) : 0u;
      uint dlo = e & 63u;
      float ds = dis[src];                 // 200KB table: L2-hot
      uint4 hv = hw4[src * 8 + l8];        // 8 rows in flight per instr
      if (v) {
        float* ap = &accL[dlo * 65 + l8 * 8];
        atomicAdd(&ap[0], ds * blo(hv.x));
        atomicAdd(&ap[1], ds * bhi(hv.x));
        atomicAdd(&ap[2], ds * blo(hv.y));
        atomicAdd(&ap[3], ds * bhi(hv.y));
        atomicAdd(&ap[4], ds * blo(hv.z));
        atomicAdd(&ap[5], ds * bhi(hv.z));
        atomicAdd(&ap[6], ds * blo(hv.w));
        atomicAdd(&ap[7], ds * bhi(hv.w));
      }
    }
  }
  __syncthreads();
  // epilogue: pre = dis_n*(acc + dis_n*h[n]) + bias; store bf16; BN stats
  int f = lane;
  float bf = bias[f];
  float lsum = 0.f, lsq = 0.f;
  int nb = b << 6;
  for (int r = wid; r < 64; r += 4) {
    int n = nb + r;
    if (n >= N_NODES) break;
    float dn = dis[n];
    ushort hu = ((const ushort*)hW)[(n << 6) + f];
    float hval = __uint_as_float((uint)hu << 16);
    float pre = fmaf(dn, accL[r * 65 + f] + dn * hval, bf);
    __builtin_nontemporal_store(f2b(pre), &((ushort*)act)[(n << 6) + f]);
    lsum += pre;
    lsq = fmaf(pre, pre, lsq);
  }
  ssum[wid][f] = lsum;
  ssq[wid][f] = lsq;
  __syncthreads();
  if (tid < 64) {
    float s4 = ssum[0][tid] + ssum[1][tid] + ssum[2][tid] + ssum[3][tid];
    float q4 = ssq[0][tid] + ssq[1][tid] + ssq[2][tid] + ssq[3][tid];
    float* sl = stats + (b & 7) * 128;  // 8-way de-contended
    atomicAdd(&sl[tid], s4);
    atomicAdd(&sl[64 + tid], q4);
  }
}

// ---------------- pool + MLP ----------------

__global__ __launch_bounds__(256) void k_pool(const __hip_bfloat16* __restrict__ act,
                                              const float* __restrict__ stats_in,
                                              const float* __restrict__ gamma,
                                              const float* __restrict__ beta,
                                              float* __restrict__ pooled) {
  int g = blockIdx.x;
  int tid = threadIdx.x;
  int l16 = tid & 15;  // feats 4*l16 .. 4*l16+3
  int r = tid >> 4;    // 16 row-slices
  float sc[4], sh[4];
#pragma unroll
  for (int i = 0; i < 4; ++i) {
    int f = l16 * 4 + i;
    float s = 0.f, q = 0.f;
#pragma unroll
    for (int c = 0; c < 8; ++c) {
      s += stats_in[c * 128 + f];
      q += stats_in[c * 128 + 64 + f];
    }
    float mu = s * (1.0f / N_NODES);
    float var = q * (1.0f / N_NODES) - mu * mu;
    sc[i] = gamma[f] * rsqrtf(var + BN_EPS);
    sh[i] = beta[f] - mu * sc[i];
  }
  int gs = g * N_NODES;
  int start = (gs + 63) >> 6;
  int end = (gs + N_NODES + 63) >> 6;
  float m[4] = {0.f, 0.f, 0.f, 0.f};  // post-ReLU >= 0
  const uint2* a2 = (const uint2*)act;
  for (int n = start + r; n < end; n += 16) {
    uint2 v = a2[n * 16 + l16];
    m[0] = fmaxf(m[0], fmaf(blo(v.x), sc[0], sh[0]));
    m[1] = fmaxf(m[1], fmaf(bhi(v.x), sc[1], sh[1]));
    m[2] = fmaxf(m[2], fmaf(blo(v.y), sc[2], sh[2]));
    m[3] = fmaxf(m[3], fmaf(bhi(v.y), sc[3], sh[3]));
  }
  __shared__ float sm[16][64];
#pragma unroll
  for (int i = 0; i < 4; ++i) sm[r][l16 * 4 + i] = m[i];
  __syncthreads();
  if (tid < 64) {
    float mm = sm[0][tid];
#pragma unroll
    for (int rr = 1; rr < 16; ++rr) mm = fmaxf(mm, sm[rr][tid]);
    pooled[g * 64 + tid] = mm;
  }
}

__global__ __launch_bounds__(256) void k_final(const float* __restrict__ pooled,
                                               const float* __restrict__ w1,
                                               const float* __restrict__ b1,
                                               const float* __restrict__ w2,
                                               const float* __restrict__ b2,
                                               float* __restrict__ out) {
  __shared__ float P[64 * 64];
  __shared__ float Hd[64 * 64];
  int tid = threadIdx.x;
  for (int i = tid; i < 4096; i += 256) P[i] = pooled[i];
  __syncthreads();
  for (int i = tid; i < 4096; i += 256) {
    int g = i >> 6, j = i & 63;
    float acc = b1[j];
#pragma unroll
    for (int k = 0; k < 64; ++k) acc = fmaf(P[g * 64 + k], w1[k * 64 + j], acc);
    Hd[i] = acc > 0.f ? acc : 0.f;
  }
  __syncthreads();
  for (int i = tid; i < 640; i += 256) {
    int g = i / 10, c = i % 10;
    float acc = b2[c];
#pragma unroll
    for (int k = 0; k < 64; ++k) acc = fmaf(Hd[g * 64 + k], w2[k * 10 + c], acc);
    out[i] = acc;
  }
}

// ---------------- launch ----------------

extern "C" void kernel_launch(void* const* d_in, const int* in_sizes, int n_in,
                              void* d_out, int out_size, void* d_ws, size_t ws_size,
                              hipStream_t stream) {
  const float* x = (const float*)d_in[0];
  const int* ei = (const int*)d_in[1];
  const float* W1 = (const float*)d_in[3];
  const float* b1 = (const float*)d_in[4];
  const float* W2 = (const float*)d_in[5];
  const float* b2 = (const float*)d_in[6];
  const float* W3 = (const float*)d_in[7];
  const float* b3 = (const float*)d_in[8];
  const float* gamma = (const float*)d_in[9];
  const float* beta = (const float*)d_in[10];
  const float* l1w = (const float*)d_in[11];
  const float* l1b = (const float*)d_in[12];
  const float* l2w = (const float*)d_in[13];
  const float* l2b = (const float*)d_in[14];
  float* out = (float*)d_out;

  char* ws = (char*)d_ws;
  size_t off = 0;
  auto alloc = [&](size_t bytes) {
    void* p = ws + off;
    off = (off + bytes + 255) & ~(size_t)255;
    return p;
  };
  int* deg = (int*)alloc(N_NODES * 4);
  int* bktsum = (int*)alloc(NBKT * 4);
  int* bro = (int*)alloc((NBKT + 1) * 4);
  int* bcur = (int*)alloc(NBKT * 4);
  uint* edata = (uint*)alloc((size_t)N_EDGES * 4);
  float* dis = (float*)alloc(N_NODES * 4);
  __hip_bfloat16* hW = (__hip_bfloat16*)alloc((size_t)N_NODES * 64 * 2);
  __hip_bfloat16* act = (__hip_bfloat16*)alloc((size_t)N_NODES * 64 * 2);
  float* statsL0 = (float*)alloc(1024 * 4);
  float* statsL1 = (float*)alloc(1024 * 4);
  float* statsL2 = (float*)alloc(1024 * 4);
  float* pooled = (float*)alloc(4096 * 4);

  (void)hipMemsetAsync(deg, 0, N_NODES * 4, stream);
  k_count_deg<<<(N_EDGES + 255) / 256, 256, 0, stream>>>(ei + N_EDGES, deg);
  k_dis_bkt<<<196, 256, 0, stream>>>(deg, dis, bktsum);
  k_scan_bkt<<<1, 256, 0, stream>>>(bktsum, bro, bcur);
  k_fill<<<FILL_BLOCKS, 256, 0, stream>>>(ei, bcur, edata);

  // layer 1
  k_gemm<false><<<2048, 256, 0, stream>>>(x, W1, hW, statsL0, nullptr, gamma, beta);
  k_agg_bkt<<<NBKT, 256, 0, stream>>>(hW, dis, bro, edata, b1, act, statsL0);
  // layer 2
  k_gemm<true><<<2048, 256, 0, stream>>>(act, W2, hW, statsL1, statsL0, gamma, beta);
  k_agg_bkt<<<NBKT, 256, 0, stream>>>(hW, dis, bro, edata, b2, act, statsL1);
  // layer 3
  k_gemm<true><<<2048, 256, 0, stream>>>(act, W3, hW, statsL2, statsL1, gamma, beta);
  k_agg_bkt<<<NBKT, 256, 0, stream>>>(hW, dis, bro, edata, b3, act, statsL2);

  k_pool<<<N_GRAPHS, 256, 0, stream>>>(act, statsL2, gamma, beta, pooled);
  k_final<<<1, 256, 0, stream>>>(pooled, l1w, l1b, l2w, l2b, out);
}

// Round 10
// 230.117 us; speedup vs baseline: 5.2628x; 5.2628x over previous
//
#include <hip/hip_runtime.h>
#include <hip/hip_bf16.h>

#define N_NODES 50000
#define N_EDGES 800000
#define HID 64
#define N_GRAPHS 64
#define N_CLASSES 10
#define BN_EPS 1e-5f

typedef unsigned int uint;
typedef unsigned short ushort;

__device__ __forceinline__ float blo(uint u) { return __uint_as_float(u << 16); }
__device__ __forceinline__ float bhi(uint u) { return __uint_as_float(u & 0xffff0000u); }
__device__ __forceinline__ unsigned short f2b(float f) {
  __hip_bfloat16 h = __float2bfloat16(f);
  return *reinterpret_cast<unsigned short*>(&h);
}

// ---------------- CSR build (R6 pipeline, proven) ----------------

__global__ void k_count_deg(const int* __restrict__ dst, int* __restrict__ deg) {
  int e = blockIdx.x * blockDim.x + threadIdx.x;
  if (e < N_EDGES) atomicAdd(&deg[__builtin_nontemporal_load(&dst[e])], 1);
}

__global__ void k_scan_block(const int* __restrict__ deg, int* __restrict__ rowp,
                             int* __restrict__ bsum, float* __restrict__ dis) {
  __shared__ int s[256];
  int tid = threadIdx.x;
  int i = blockIdx.x * 256 + tid;
  int v = (i < N_NODES) ? deg[i] : 0;
  if (i < N_NODES) dis[i] = rsqrtf((float)v + 1.0f);
  s[tid] = v;
  __syncthreads();
  for (int off = 1; off < 256; off <<= 1) {
    int t = (tid >= off) ? s[tid - off] : 0;
    __syncthreads();
    s[tid] += t;
    __syncthreads();
  }
  if (i < N_NODES) rowp[i] = s[tid] - v;
  if (tid == 255) bsum[blockIdx.x] = s[255];
}

__global__ void k_scan_partials(int* __restrict__ bsum, int nb) {
  __shared__ int s[256];
  int tid = threadIdx.x;
  int v = (tid < nb) ? bsum[tid] : 0;
  s[tid] = v;
  __syncthreads();
  for (int off = 1; off < 256; off <<= 1) {
    int t = (tid >= off) ? s[tid - off] : 0;
    __syncthreads();
    s[tid] += t;
    __syncthreads();
  }
  if (tid < nb) bsum[tid] = s[tid] - v;
}

__global__ void k_scan_finish(int* __restrict__ rowp, const int* __restrict__ bsum,
                              int* __restrict__ cursor) {
  int i = blockIdx.x * blockDim.x + threadIdx.x;
  if (i < N_NODES) {
    int v = rowp[i] + bsum[i >> 8];
    rowp[i] = v;
    cursor[i] = v;
  }
  if (i == 0) rowp[N_NODES] = N_EDGES;
}

// pack {src:16 | bf16(coef):16} per edge, grouped by dst
__global__ void k_fill_edges(const int* __restrict__ ei, const float* __restrict__ dis,
                             int* __restrict__ cursor, uint* __restrict__ edata) {
  int e = blockIdx.x * blockDim.x + threadIdx.x;
  if (e < N_EDGES) {
    int s = __builtin_nontemporal_load(&ei[e]);
    int d = __builtin_nontemporal_load(&ei[N_EDGES + e]);
    int pos = atomicAdd(&cursor[d], 1);
    edata[pos] = ((uint)s << 16) | f2b(dis[s] * dis[d]);
  }
}

// ---------------- per-layer ----------------

// out16[n][j] = bf16( sum_k bnrelu(in[n][k]) * W[k][j] )
template <bool IN_BF16>
__global__ __launch_bounds__(256) void k_gemm(const void* __restrict__ in,
                                              const float* __restrict__ W,
                                              __hip_bfloat16* __restrict__ out,
                                              float* __restrict__ stats_zero,
                                              const float* __restrict__ stats_in,
                                              const float* __restrict__ gamma,
                                              const float* __restrict__ beta) {
  __shared__ float Al[4][64];
  int tid = threadIdx.x;
  int wid = tid >> 6, f = tid & 63;
  if (blockIdx.x == 0) {
    for (int i = tid; i < 1024; i += 256) stats_zero[i] = 0.0f;
  }
  float Wreg[64];
#pragma unroll
  for (int k = 0; k < 64; ++k) Wreg[k] = W[k * 64 + f];
  float sc = 1.f, sh = 0.f;
  if (stats_in) {
    float s = 0.f, q = 0.f;
#pragma unroll
    for (int c = 0; c < 8; ++c) {
      s += stats_in[c * 128 + f];
      q += stats_in[c * 128 + 64 + f];
    }
    float mu = s * (1.0f / N_NODES);
    float var = q * (1.0f / N_NODES) - mu * mu;
    sc = gamma[f] * rsqrtf(var + BN_EPS);
    sh = beta[f] - mu * sc;
  }
  for (int n = blockIdx.x * 4 + wid; n < N_NODES; n += gridDim.x * 4) {
    float av;
    if (IN_BF16) {
      ushort u = ((const ushort*)in)[(n << 6) + f];
      av = __uint_as_float((uint)u << 16);
    } else {
      av = ((const float*)in)[(n << 6) + f];
    }
    if (stats_in) {
      av = fmaf(av, sc, sh);
      av = av > 0.f ? av : 0.f;
    }
    Al[wid][f] = av;  // same-wave LDS: ordered, no barrier
    float acc = 0.f;
    const float4* arow = (const float4*)Al[wid];
#pragma unroll
    for (int k4 = 0; k4 < 16; ++k4) {
      float4 a = arow[k4];
      acc = fmaf(a.x, Wreg[k4 * 4 + 0], acc);
      acc = fmaf(a.y, Wreg[k4 * 4 + 1], acc);
      acc = fmaf(a.z, Wreg[k4 * 4 + 2], acc);
      acc = fmaf(a.w, Wreg[k4 * 4 + 3], acc);
    }
    out[(n << 6) + f] = __float2bfloat16(acc);  // cached: gather target
  }
}

// group-per-node aggregation: 8-lane group owns one node, lane owns 8 feats.
// No per-node cross-lane reduce; 8 nodes in flight per wave.
__global__ __launch_bounds__(256, 4) void k_agg_node(
    const __hip_bfloat16* __restrict__ hW, const float* __restrict__ dis,
    const int* __restrict__ rowp, const uint* __restrict__ edata,
    const float* __restrict__ bias, __hip_bfloat16* __restrict__ act,
    float* __restrict__ stats) {
  __shared__ float sstat[4][2][64];
  int tid = threadIdx.x;
  int wid = tid >> 6, lane = tid & 63;
  int g = lane >> 3, l8 = lane & 7;
  int n = (blockIdx.x * 4 + wid) * 8 + g;  // one node per 8-lane group
  const uint4* hw4 = (const uint4*)hW;
  float pre[8] = {0, 0, 0, 0, 0, 0, 0, 0};
  float sq[8] = {0, 0, 0, 0, 0, 0, 0, 0};
  if (n < N_NODES) {
    int p0 = rowp[n], p1 = rowp[n + 1];
    float acc[8] = {0, 0, 0, 0, 0, 0, 0, 0};
    for (int pb = p0; pb < p1; pb += 8) {
      uint rec = (pb + l8 < p1) ? edata[pb + l8] : 0u;  // 8 recs per group
      uint e[8];
#pragma unroll
      for (int u = 0; u < 8; ++u) e[u] = __shfl(rec, (g << 3) | u, 64);
      // gathers in 2 batches of 4 (caps VGPR at hv[4])
#pragma unroll
      for (int h = 0; h < 2; ++h) {
        uint4 hv[4];
#pragma unroll
        for (int u = 0; u < 4; ++u) hv[u] = hw4[(e[h * 4 + u] >> 16) * 8 + l8];
#pragma unroll
        for (int u = 0; u < 4; ++u) {
          float wv = blo(e[h * 4 + u]);  // 0 for padded slots
          acc[0] = fmaf(blo(hv[u].x), wv, acc[0]);
          acc[1] = fmaf(bhi(hv[u].x), wv, acc[1]);
          acc[2] = fmaf(blo(hv[u].y), wv, acc[2]);
          acc[3] = fmaf(bhi(hv[u].y), wv, acc[3]);
          acc[4] = fmaf(blo(hv[u].z), wv, acc[4]);
          acc[5] = fmaf(bhi(hv[u].z), wv, acc[5]);
          acc[6] = fmaf(blo(hv[u].w), wv, acc[6]);
          acc[7] = fmaf(bhi(hv[u].w), wv, acc[7]);
        }
      }
    }
    float dn = dis[n];
    float dn2 = dn * dn;
    uint4 hs = hw4[n * 8 + l8];
    const float4* b4 = (const float4*)bias;
    float4 bA = b4[l8 * 2], bB = b4[l8 * 2 + 1];
    pre[0] = fmaf(blo(hs.x), dn2, acc[0]) + bA.x;
    pre[1] = fmaf(bhi(hs.x), dn2, acc[1]) + bA.y;
    pre[2] = fmaf(blo(hs.y), dn2, acc[2]) + bA.z;
    pre[3] = fmaf(bhi(hs.y), dn2, acc[3]) + bA.w;
    pre[4] = fmaf(blo(hs.z), dn2, acc[4]) + bB.x;
    pre[5] = fmaf(bhi(hs.z), dn2, acc[5]) + bB.y;
    pre[6] = fmaf(blo(hs.w), dn2, acc[6]) + bB.z;
    pre[7] = fmaf(bhi(hs.w), dn2, acc[7]) + bB.w;
    uint4 st;
    st.x = (uint)f2b(pre[0]) | ((uint)f2b(pre[1]) << 16);
    st.y = (uint)f2b(pre[2]) | ((uint)f2b(pre[3]) << 16);
    st.z = (uint)f2b(pre[4]) | ((uint)f2b(pre[5]) << 16);
    st.w = (uint)f2b(pre[6]) | ((uint)f2b(pre[7]) << 16);
    ((uint4*)act)[n * 8 + l8] = st;  // group stores contiguous 128B
#pragma unroll
    for (int i = 0; i < 8; ++i) sq[i] = pre[i] * pre[i];
  }
  // one cross-group reduce per wave (feats at lanes l8, l8+8, ..., l8+56)
#pragma unroll
  for (int off = 8; off < 64; off <<= 1) {
#pragma unroll
    for (int i = 0; i < 8; ++i) {
      pre[i] += __shfl_xor(pre[i], off, 64);
      sq[i] += __shfl_xor(sq[i], off, 64);
    }
  }
  if (g == 0) {
#pragma unroll
    for (int i = 0; i < 8; ++i) {
      sstat[wid][0][l8 * 8 + i] = pre[i];
      sstat[wid][1][l8 * 8 + i] = sq[i];
    }
  }
  __syncthreads();
  if (tid < 128) {
    int which = tid >> 6, f = tid & 63;
    float s = sstat[0][which][f] + sstat[1][which][f] + sstat[2][which][f] +
              sstat[3][which][f];
    atomicAdd(&stats[(blockIdx.x & 7) * 128 + which * 64 + f], s);
  }
}

// ---------------- pool + MLP ----------------

__global__ __launch_bounds__(256) void k_pool(const __hip_bfloat16* __restrict__ act,
                                              const float* __restrict__ stats_in,
                                              const float* __restrict__ gamma,
                                              const float* __restrict__ beta,
                                              float* __restrict__ pooled) {
  int g = blockIdx.x;
  int tid = threadIdx.x;
  int l16 = tid & 15;  // feats 4*l16 .. 4*l16+3
  int r = tid >> 4;    // 16 row-slices
  float sc[4], sh[4];
#pragma unroll
  for (int i = 0; i < 4; ++i) {
    int f = l16 * 4 + i;
    float s = 0.f, q = 0.f;
#pragma unroll
    for (int c = 0; c < 8; ++c) {
      s += stats_in[c * 128 + f];
      q += stats_in[c * 128 + 64 + f];
    }
    float mu = s * (1.0f / N_NODES);
    float var = q * (1.0f / N_NODES) - mu * mu;
    sc[i] = gamma[f] * rsqrtf(var + BN_EPS);
    sh[i] = beta[f] - mu * sc[i];
  }
  int gs = g * N_NODES;
  int start = (gs + 63) >> 6;
  int end = (gs + N_NODES + 63) >> 6;
  float m[4] = {0.f, 0.f, 0.f, 0.f};  // post-ReLU >= 0
  const uint2* a2 = (const uint2*)act;
  for (int n = start + r; n < end; n += 16) {
    uint2 v = a2[n * 16 + l16];
    m[0] = fmaxf(m[0], fmaf(blo(v.x), sc[0], sh[0]));
    m[1] = fmaxf(m[1], fmaf(bhi(v.x), sc[1], sh[1]));
    m[2] = fmaxf(m[2], fmaf(blo(v.y), sc[2], sh[2]));
    m[3] = fmaxf(m[3], fmaf(bhi(v.y), sc[3], sh[3]));
  }
  __shared__ float sm[16][64];
#pragma unroll
  for (int i = 0; i < 4; ++i) sm[r][l16 * 4 + i] = m[i];
  __syncthreads();
  if (tid < 64) {
    float mm = sm[0][tid];
#pragma unroll
    for (int rr = 1; rr < 16; ++rr) mm = fmaxf(mm, sm[rr][tid]);
    pooled[g * 64 + tid] = mm;
  }
}

__global__ __launch_bounds__(256) void k_final(const float* __restrict__ pooled,
                                               const float* __restrict__ w1,
                                               const float* __restrict__ b1,
                                               const float* __restrict__ w2,
                                               const float* __restrict__ b2,
                                               float* __restrict__ out) {
  __shared__ float P[64 * 64];
  __shared__ float Hd[64 * 64];
  int tid = threadIdx.x;
  for (int i = tid; i < 4096; i += 256) P[i] = pooled[i];
  __syncthreads();
  for (int i = tid; i < 4096; i += 256) {
    int g = i >> 6, j = i & 63;
    float acc = b1[j];
#pragma unroll
    for (int k = 0; k < 64; ++k) acc = fmaf(P[g * 64 + k], w1[k * 64 + j], acc);
    Hd[i] = acc > 0.f ? acc : 0.f;
  }
  __syncthreads();
  for (int i = tid; i < 640; i += 256) {
    int g = i / 10, c = i % 10;
    float acc = b2[c];
#pragma unroll
    for (int k = 0; k < 64; ++k) acc = fmaf(Hd[g * 64 + k], w2[k * 10 + c], acc);
    out[i] = acc;
  }
}

// ---------------- launch ----------------

extern "C" void kernel_launch(void* const* d_in, const int* in_sizes, int n_in,
                              void* d_out, int out_size, void* d_ws, size_t ws_size,
                              hipStream_t stream) {
  const float* x = (const float*)d_in[0];
  const int* ei = (const int*)d_in[1];
  const float* W1 = (const float*)d_in[3];
  const float* b1 = (const float*)d_in[4];
  const float* W2 = (const float*)d_in[5];
  const float* b2 = (const float*)d_in[6];
  const float* W3 = (const float*)d_in[7];
  const float* b3 = (const float*)d_in[8];
  const float* gamma = (const float*)d_in[9];
  const float* beta = (const float*)d_in[10];
  const float* l1w = (const float*)d_in[11];
  const float* l1b = (const float*)d_in[12];
  const float* l2w = (const float*)d_in[13];
  const float* l2b = (const float*)d_in[14];
  float* out = (float*)d_out;

  char* ws = (char*)d_ws;
  size_t off = 0;
  auto alloc = [&](size_t bytes) {
    void* p = ws + off;
    off = (off + bytes + 255) & ~(size_t)255;
    return p;
  };
  int* deg = (int*)alloc(N_NODES * 4);
  int* rowp = (int*)alloc((N_NODES + 1) * 4);
  int* cursor = (int*)alloc(N_NODES * 4);
  int* bsum = (int*)alloc(256 * 4);
  uint* edata = (uint*)alloc((size_t)N_EDGES * 4);
  float* dis = (float*)alloc(N_NODES * 4);
  __hip_bfloat16* hW = (__hip_bfloat16*)alloc((size_t)N_NODES * 64 * 2);
  __hip_bfloat16* act = (__hip_bfloat16*)alloc((size_t)N_NODES * 64 * 2);
  float* statsL0 = (float*)alloc(1024 * 4);
  float* statsL1 = (float*)alloc(1024 * 4);
  float* statsL2 = (float*)alloc(1024 * 4);
  float* pooled = (float*)alloc(4096 * 4);

  int nsb = (N_NODES + 255) / 256;   // 196
  int nag = (N_NODES + 31) / 32;     // 1563 blocks, 1 node per 8-lane group

  (void)hipMemsetAsync(deg, 0, N_NODES * 4, stream);
  k_count_deg<<<(N_EDGES + 255) / 256, 256, 0, stream>>>(ei + N_EDGES, deg);
  k_scan_block<<<nsb, 256, 0, stream>>>(deg, rowp, bsum, dis);
  k_scan_partials<<<1, 256, 0, stream>>>(bsum, nsb);
  k_scan_finish<<<nsb, 256, 0, stream>>>(rowp, bsum, cursor);
  k_fill_edges<<<(N_EDGES + 255) / 256, 256, 0, stream>>>(ei, dis, cursor, edata);

  // layer 1
  k_gemm<false><<<2048, 256, 0, stream>>>(x, W1, hW, statsL0, nullptr, gamma, beta);
  k_agg_node<<<nag, 256, 0, stream>>>(hW, dis, rowp, edata, b1, act, statsL0);
  // layer 2
  k_gemm<true><<<2048, 256, 0, stream>>>(act, W2, hW, statsL1, statsL0, gamma, beta);
  k_agg_node<<<nag, 256, 0, stream>>>(hW, dis, rowp, edata, b2, act, statsL1);
  // layer 3
  k_gemm<true><<<2048, 256, 0, stream>>>(act, W3, hW, statsL2, statsL1, gamma, beta);
  k_agg_node<<<nag, 256, 0, stream>>>(hW, dis, rowp, edata, b3, act, statsL2);

  k_pool<<<N_GRAPHS, 256, 0, stream>>>(act, statsL2, gamma, beta, pooled);
  k_final<<<1, 256, 0, stream>>>(pooled, l1w, l1b, l2w, l2b, out);
}

// Round 11
// 226.966 us; speedup vs baseline: 5.3359x; 1.0139x over previous
//
#include <hip/hip_runtime.h>
#include <hip/hip_bf16.h>

#define N_NODES 50000
#define N_EDGES 800000
#define HID 64
#define N_GRAPHS 64
#define N_CLASSES 10
#define BN_EPS 1e-5f
#define NPART 196          // ceil(50000/256) partitions of 256 dst nodes
#define FILL_BLOCKS 128

typedef unsigned int uint;
typedef unsigned short ushort;

__device__ __forceinline__ float blo(uint u) { return __uint_as_float(u << 16); }
__device__ __forceinline__ float bhi(uint u) { return __uint_as_float(u & 0xffff0000u); }
__device__ __forceinline__ unsigned short f2b(float f) {
  __hip_bfloat16 h = __float2bfloat16(f);
  return *reinterpret_cast<unsigned short*>(&h);
}

// ---------------- CSR build ----------------

__global__ void k_count_deg(const int* __restrict__ dst, int* __restrict__ deg) {
  int e = blockIdx.x * blockDim.x + threadIdx.x;
  if (e < N_EDGES) atomicAdd(&deg[__builtin_nontemporal_load(&dst[e])], 1);
}

__global__ void k_scan_block(const int* __restrict__ deg, int* __restrict__ rowp,
                             int* __restrict__ bsum, float* __restrict__ dis) {
  __shared__ int s[256];
  int tid = threadIdx.x;
  int i = blockIdx.x * 256 + tid;
  int v = (i < N_NODES) ? deg[i] : 0;
  if (i < N_NODES) dis[i] = rsqrtf((float)v + 1.0f);
  s[tid] = v;
  __syncthreads();
  for (int off = 1; off < 256; off <<= 1) {
    int t = (tid >= off) ? s[tid - off] : 0;
    __syncthreads();
    s[tid] += t;
    __syncthreads();
  }
  if (i < N_NODES) rowp[i] = s[tid] - v;
  if (tid == 255) bsum[blockIdx.x] = s[255];
}

__global__ void k_scan_partials(int* __restrict__ bsum, int nb) {
  __shared__ int s[256];
  int tid = threadIdx.x;
  int v = (tid < nb) ? bsum[tid] : 0;
  s[tid] = v;
  __syncthreads();
  for (int off = 1; off < 256; off <<= 1) {
    int t = (tid >= off) ? s[tid - off] : 0;
    __syncthreads();
    s[tid] += t;
    __syncthreads();
  }
  if (tid < nb) bsum[tid] = s[tid] - v;
}

// finish rowp; also init per-partition cursors pcur[p] = rowp[p*256]
__global__ void k_scan_finish(int* __restrict__ rowp, const int* __restrict__ bsum,
                              int* __restrict__ pcur) {
  int i = blockIdx.x * blockDim.x + threadIdx.x;
  if (i < N_NODES) {
    int v = rowp[i] + bsum[i >> 8];
    rowp[i] = v;
    if ((i & 255) == 0) pcur[i >> 8] = v;
  }
  if (i == 0) rowp[N_NODES] = N_EDGES;
}

// Pass A: partition edges by dst>>8; per-block LDS histogram + reservation.
// tmp record = src<<8 | (dst & 255)  (24 bits used)
__global__ __launch_bounds__(256) void k_partA(const int* __restrict__ ei,
                                               int* __restrict__ pcur,
                                               uint* __restrict__ tmp) {
  __shared__ int lcnt[NPART];
  __shared__ int lbase[NPART];
  int tid = threadIdx.x;
  const int per = (N_EDGES + FILL_BLOCKS - 1) / FILL_BLOCKS;  // 6250
  int c0 = blockIdx.x * per;
  int c1 = c0 + per;
  if (c1 > N_EDGES) c1 = N_EDGES;
  for (int i = tid; i < NPART; i += 256) lcnt[i] = 0;
  __syncthreads();
  for (int e = c0 + tid; e < c1; e += 256) {
    int d = __builtin_nontemporal_load(&ei[N_EDGES + e]);
    atomicAdd(&lcnt[d >> 8], 1);
  }
  __syncthreads();
  for (int p = tid; p < NPART; p += 256) lbase[p] = atomicAdd(&pcur[p], lcnt[p]);
  __syncthreads();
  for (int e = c0 + tid; e < c1; e += 256) {
    int s = __builtin_nontemporal_load(&ei[e]);
    int d = __builtin_nontemporal_load(&ei[N_EDGES + e]);
    int pos = atomicAdd(&lbase[d >> 8], 1);
    tmp[pos] = ((uint)s << 8) | (uint)(d & 255);  // grouped runs: L2 merges
  }
}

// Pass B: one block per partition; place records at final CSR positions.
// All writes fall in this block's private window -> single-XCD L2 merge.
__global__ __launch_bounds__(256) void k_partB(const uint* __restrict__ tmp,
                                               const int* __restrict__ rowp,
                                               const float* __restrict__ dis,
                                               uint* __restrict__ edata) {
  __shared__ int cur[256];
  __shared__ float sdis[256];
  int tid = threadIdx.x;
  int p = blockIdx.x;
  int n0 = p << 8;
  {
    int n = n0 + tid;
    cur[tid] = (n < N_NODES) ? rowp[n] : 0;
    sdis[tid] = (n < N_NODES) ? dis[n] : 0.f;
  }
  int base = rowp[n0];
  int endn = n0 + 256;
  if (endn > N_NODES) endn = N_NODES;
  int pend = rowp[endn];
  __syncthreads();
  for (int idx = base + tid; idx < pend; idx += 256) {
    uint t = __builtin_nontemporal_load(&tmp[idx]);
    uint s = t >> 8;
    uint dl = t & 255u;
    int pos = atomicAdd(&cur[dl], 1);
    float coef = dis[s] * sdis[dl];
    edata[pos] = (s << 16) | (uint)f2b(coef);
  }
}

// ---------------- per-layer ----------------

// out16[n][j] = bf16( sum_k bnrelu(in[n][k]) * W[k][j] )
template <bool IN_BF16>
__global__ __launch_bounds__(256) void k_gemm(const void* __restrict__ in,
                                              const float* __restrict__ W,
                                              __hip_bfloat16* __restrict__ out,
                                              float* __restrict__ stats_zero,
                                              const float* __restrict__ stats_in,
                                              const float* __restrict__ gamma,
                                              const float* __restrict__ beta) {
  __shared__ float Al[4][64];
  int tid = threadIdx.x;
  int wid = tid >> 6, f = tid & 63;
  if (blockIdx.x == 0) {
    for (int i = tid; i < 1024; i += 256) stats_zero[i] = 0.0f;
  }
  float Wreg[64];
#pragma unroll
  for (int k = 0; k < 64; ++k) Wreg[k] = W[k * 64 + f];
  float sc = 1.f, sh = 0.f;
  if (stats_in) {
    float s = 0.f, q = 0.f;
#pragma unroll
    for (int c = 0; c < 8; ++c) {
      s += stats_in[c * 128 + f];
      q += stats_in[c * 128 + 64 + f];
    }
    float mu = s * (1.0f / N_NODES);
    float var = q * (1.0f / N_NODES) - mu * mu;
    sc = gamma[f] * rsqrtf(var + BN_EPS);
    sh = beta[f] - mu * sc;
  }
  for (int n = blockIdx.x * 4 + wid; n < N_NODES; n += gridDim.x * 4) {
    float av;
    if (IN_BF16) {
      ushort u = ((const ushort*)in)[(n << 6) + f];
      av = __uint_as_float((uint)u << 16);
    } else {
      av = ((const float*)in)[(n << 6) + f];
    }
    if (stats_in) {
      av = fmaf(av, sc, sh);
      av = av > 0.f ? av : 0.f;
    }
    Al[wid][f] = av;  // same-wave LDS: ordered, no barrier
    float acc = 0.f;
    const float4* arow = (const float4*)Al[wid];
#pragma unroll
    for (int k4 = 0; k4 < 16; ++k4) {
      float4 a = arow[k4];
      acc = fmaf(a.x, Wreg[k4 * 4 + 0], acc);
      acc = fmaf(a.y, Wreg[k4 * 4 + 1], acc);
      acc = fmaf(a.z, Wreg[k4 * 4 + 2], acc);
      acc = fmaf(a.w, Wreg[k4 * 4 + 3], acc);
    }
    out[(n << 6) + f] = __float2bfloat16(acc);  // cached: gather target
  }
}

// group-per-node aggregation: 8-lane group owns one node, lane owns 8 feats.
__global__ __launch_bounds__(256, 4) void k_agg_node(
    const __hip_bfloat16* __restrict__ hW, const float* __restrict__ dis,
    const int* __restrict__ rowp, const uint* __restrict__ edata,
    const float* __restrict__ bias, __hip_bfloat16* __restrict__ act,
    float* __restrict__ stats) {
  __shared__ float sstat[4][2][64];
  int tid = threadIdx.x;
  int wid = tid >> 6, lane = tid & 63;
  int g = lane >> 3, l8 = lane & 7;
  int n = (blockIdx.x * 4 + wid) * 8 + g;  // one node per 8-lane group
  const uint4* hw4 = (const uint4*)hW;
  float pre[8] = {0, 0, 0, 0, 0, 0, 0, 0};
  float sq[8] = {0, 0, 0, 0, 0, 0, 0, 0};
  if (n < N_NODES) {
    int p0 = rowp[n], p1 = rowp[n + 1];
    float acc[8] = {0, 0, 0, 0, 0, 0, 0, 0};
    for (int pb = p0; pb < p1; pb += 8) {
      uint rec = (pb + l8 < p1) ? edata[pb + l8] : 0u;  // 8 recs per group
      uint e[8];
#pragma unroll
      for (int u = 0; u < 8; ++u) e[u] = __shfl(rec, (g << 3) | u, 64);
#pragma unroll
      for (int h = 0; h < 2; ++h) {
        uint4 hv[4];
#pragma unroll
        for (int u = 0; u < 4; ++u) hv[u] = hw4[(e[h * 4 + u] >> 16) * 8 + l8];
#pragma unroll
        for (int u = 0; u < 4; ++u) {
          float wv = blo(e[h * 4 + u]);  // 0 for padded slots
          acc[0] = fmaf(blo(hv[u].x), wv, acc[0]);
          acc[1] = fmaf(bhi(hv[u].x), wv, acc[1]);
          acc[2] = fmaf(blo(hv[u].y), wv, acc[2]);
          acc[3] = fmaf(bhi(hv[u].y), wv, acc[3]);
          acc[4] = fmaf(blo(hv[u].z), wv, acc[4]);
          acc[5] = fmaf(bhi(hv[u].z), wv, acc[5]);
          acc[6] = fmaf(blo(hv[u].w), wv, acc[6]);
          acc[7] = fmaf(bhi(hv[u].w), wv, acc[7]);
        }
      }
    }
    float dn = dis[n];
    float dn2 = dn * dn;
    uint4 hs = hw4[n * 8 + l8];
    const float4* b4 = (const float4*)bias;
    float4 bA = b4[l8 * 2], bB = b4[l8 * 2 + 1];
    pre[0] = fmaf(blo(hs.x), dn2, acc[0]) + bA.x;
    pre[1] = fmaf(bhi(hs.x), dn2, acc[1]) + bA.y;
    pre[2] = fmaf(blo(hs.y), dn2, acc[2]) + bA.z;
    pre[3] = fmaf(bhi(hs.y), dn2, acc[3]) + bA.w;
    pre[4] = fmaf(blo(hs.z), dn2, acc[4]) + bB.x;
    pre[5] = fmaf(bhi(hs.z), dn2, acc[5]) + bB.y;
    pre[6] = fmaf(blo(hs.w), dn2, acc[6]) + bB.z;
    pre[7] = fmaf(bhi(hs.w), dn2, acc[7]) + bB.w;
    uint4 st;
    st.x = (uint)f2b(pre[0]) | ((uint)f2b(pre[1]) << 16);
    st.y = (uint)f2b(pre[2]) | ((uint)f2b(pre[3]) << 16);
    st.z = (uint)f2b(pre[4]) | ((uint)f2b(pre[5]) << 16);
    st.w = (uint)f2b(pre[6]) | ((uint)f2b(pre[7]) << 16);
    ((uint4*)act)[n * 8 + l8] = st;  // group stores contiguous 128B
#pragma unroll
    for (int i = 0; i < 8; ++i) sq[i] = pre[i] * pre[i];
  }
  // one cross-group reduce per wave
#pragma unroll
  for (int off = 8; off < 64; off <<= 1) {
#pragma unroll
    for (int i = 0; i < 8; ++i) {
      pre[i] += __shfl_xor(pre[i], off, 64);
      sq[i] += __shfl_xor(sq[i], off, 64);
    }
  }
  if (g == 0) {
#pragma unroll
    for (int i = 0; i < 8; ++i) {
      sstat[wid][0][l8 * 8 + i] = pre[i];
      sstat[wid][1][l8 * 8 + i] = sq[i];
    }
  }
  __syncthreads();
  if (tid < 128) {
    int which = tid >> 6, f = tid & 63;
    float s = sstat[0][which][f] + sstat[1][which][f] + sstat[2][which][f] +
              sstat[3][which][f];
    atomicAdd(&stats[(blockIdx.x & 7) * 128 + which * 64 + f], s);
  }
}

// ---------------- pool + MLP ----------------

__global__ __launch_bounds__(256) void k_pool(const __hip_bfloat16* __restrict__ act,
                                              const float* __restrict__ stats_in,
                                              const float* __restrict__ gamma,
                                              const float* __restrict__ beta,
                                              float* __restrict__ pooled) {
  int g = blockIdx.x;
  int tid = threadIdx.x;
  int l16 = tid & 15;  // feats 4*l16 .. 4*l16+3
  int r = tid >> 4;    // 16 row-slices
  float sc[4], sh[4];
#pragma unroll
  for (int i = 0; i < 4; ++i) {
    int f = l16 * 4 + i;
    float s = 0.f, q = 0.f;
#pragma unroll
    for (int c = 0; c < 8; ++c) {
      s += stats_in[c * 128 + f];
      q += stats_in[c * 128 + 64 + f];
    }
    float mu = s * (1.0f / N_NODES);
    float var = q * (1.0f / N_NODES) - mu * mu;
    sc[i] = gamma[f] * rsqrtf(var + BN_EPS);
    sh[i] = beta[f] - mu * sc[i];
  }
  int gs = g * N_NODES;
  int start = (gs + 63) >> 6;
  int end = (gs + N_NODES + 63) >> 6;
  float m[4] = {0.f, 0.f, 0.f, 0.f};  // post-ReLU >= 0
  const uint2* a2 = (const uint2*)act;
  for (int n = start + r; n < end; n += 16) {
    uint2 v = a2[n * 16 + l16];
    m[0] = fmaxf(m[0], fmaf(blo(v.x), sc[0], sh[0]));
    m[1] = fmaxf(m[1], fmaf(bhi(v.x), sc[1], sh[1]));
    m[2] = fmaxf(m[2], fmaf(blo(v.y), sc[2], sh[2]));
    m[3] = fmaxf(m[3], fmaf(bhi(v.y), sc[3], sh[3]));
  }
  __shared__ float sm[16][64];
#pragma unroll
  for (int i = 0; i < 4; ++i) sm[r][l16 * 4 + i] = m[i];
  __syncthreads();
  if (tid < 64) {
    float mm = sm[0][tid];
#pragma unroll
    for (int rr = 1; rr < 16; ++rr) mm = fmaxf(mm, sm[rr][tid]);
    pooled[g * 64 + tid] = mm;
  }
}

__global__ __launch_bounds__(256) void k_final(const float* __restrict__ pooled,
                                               const float* __restrict__ w1,
                                               const float* __restrict__ b1,
                                               const float* __restrict__ w2,
                                               const float* __restrict__ b2,
                                               float* __restrict__ out) {
  __shared__ float P[64 * 64];
  __shared__ float Hd[64 * 64];
  int tid = threadIdx.x;
  for (int i = tid; i < 4096; i += 256) P[i] = pooled[i];
  __syncthreads();
  for (int i = tid; i < 4096; i += 256) {
    int g = i >> 6, j = i & 63;
    float acc = b1[j];
#pragma unroll
    for (int k = 0; k < 64; ++k) acc = fmaf(P[g * 64 + k], w1[k * 64 + j], acc);
    Hd[i] = acc > 0.f ? acc : 0.f;
  }
  __syncthreads();
  for (int i = tid; i < 640; i += 256) {
    int g = i / 10, c = i % 10;
    float acc = b2[c];
#pragma unroll
    for (int k = 0; k < 64; ++k) acc = fmaf(Hd[g * 64 + k], w2[k * 10 + c], acc);
    out[i] = acc;
  }
}

// ---------------- launch ----------------

extern "C" void kernel_launch(void* const* d_in, const int* in_sizes, int n_in,
                              void* d_out, int out_size, void* d_ws, size_t ws_size,
                              hipStream_t stream) {
  const float* x = (const float*)d_in[0];
  const int* ei = (const int*)d_in[1];
  const float* W1 = (const float*)d_in[3];
  const float* b1 = (const float*)d_in[4];
  const float* W2 = (const float*)d_in[5];
  const float* b2 = (const float*)d_in[6];
  const float* W3 = (const float*)d_in[7];
  const float* b3 = (const float*)d_in[8];
  const float* gamma = (const float*)d_in[9];
  const float* beta = (const float*)d_in[10];
  const float* l1w = (const float*)d_in[11];
  const float* l1b = (const float*)d_in[12];
  const float* l2w = (const float*)d_in[13];
  const float* l2b = (const float*)d_in[14];
  float* out = (float*)d_out;

  char* ws = (char*)d_ws;
  size_t off = 0;
  auto alloc = [&](size_t bytes) {
    void* p = ws + off;
    off = (off + bytes + 255) & ~(size_t)255;
    return p;
  };
  int* deg = (int*)alloc(N_NODES * 4);
  int* rowp = (int*)alloc((N_NODES + 1) * 4);
  int* pcur = (int*)alloc(NPART * 4);
  int* bsum = (int*)alloc(256 * 4);
  uint* tmp = (uint*)alloc((size_t)N_EDGES * 4);
  uint* edata = (uint*)alloc((size_t)N_EDGES * 4);
  float* dis = (float*)alloc(N_NODES * 4);
  __hip_bfloat16* hW = (__hip_bfloat16*)alloc((size_t)N_NODES * 64 * 2);
  __hip_bfloat16* act = (__hip_bfloat16*)alloc((size_t)N_NODES * 64 * 2);
  float* statsL0 = (float*)alloc(1024 * 4);
  float* statsL1 = (float*)alloc(1024 * 4);
  float* statsL2 = (float*)alloc(1024 * 4);
  float* pooled = (float*)alloc(4096 * 4);

  int nsb = (N_NODES + 255) / 256;   // 196
  int nag = (N_NODES + 31) / 32;     // 1563 blocks, 1 node per 8-lane group

  (void)hipMemsetAsync(deg, 0, N_NODES * 4, stream);
  k_count_deg<<<(N_EDGES + 255) / 256, 256, 0, stream>>>(ei + N_EDGES, deg);
  k_scan_block<<<nsb, 256, 0, stream>>>(deg, rowp, bsum, dis);
  k_scan_partials<<<1, 256, 0, stream>>>(bsum, nsb);
  k_scan_finish<<<nsb, 256, 0, stream>>>(rowp, bsum, pcur);
  k_partA<<<FILL_BLOCKS, 256, 0, stream>>>(ei, pcur, tmp);
  k_partB<<<NPART, 256, 0, stream>>>(tmp, rowp, dis, edata);

  // layer 1
  k_gemm<false><<<2048, 256, 0, stream>>>(x, W1, hW, statsL0, nullptr, gamma, beta);
  k_agg_node<<<nag, 256, 0, stream>>>(hW, dis, rowp, edata, b1, act, statsL0);
  // layer 2
  k_gemm<true><<<2048, 256, 0, stream>>>(act, W2, hW, statsL1, statsL0, gamma, beta);
  k_agg_node<<<nag, 256, 0, stream>>>(hW, dis, rowp, edata, b2, act, statsL1);
  // layer 3
  k_gemm<true><<<2048, 256, 0, stream>>>(act, W3, hW, statsL2, statsL1, gamma, beta);
  k_agg_node<<<nag, 256, 0, stream>>>(hW, dis, rowp, edata, b3, act, statsL2);

  k_pool<<<N_GRAPHS, 256, 0, stream>>>(act, statsL2, gamma, beta, pooled);
  k_final<<<1, 256, 0, stream>>>(pooled, l1w, l1b, l2w, l2b, out);
}

// Round 12
// 225.510 us; speedup vs baseline: 5.3703x; 1.0065x over previous
//
#include <hip/hip_runtime.h>
#include <hip/hip_bf16.h>

#define N_NODES 50000
#define N_EDGES 800000
#define HID 64
#define N_GRAPHS 64
#define N_CLASSES 10
#define BN_EPS 1e-5f
#define NPART 196          // ceil(50000/256) partitions of 256 dst nodes
#define FILL_BLOCKS 128

typedef unsigned int uint;
typedef unsigned short ushort;

__device__ __forceinline__ float blo(uint u) { return __uint_as_float(u << 16); }
__device__ __forceinline__ float bhi(uint u) { return __uint_as_float(u & 0xffff0000u); }
__device__ __forceinline__ unsigned short f2b(float f) {
  __hip_bfloat16 h = __float2bfloat16(f);
  return *reinterpret_cast<unsigned short*>(&h);
}

// ---------------- CSR build ----------------

__global__ void k_zero(int* __restrict__ p, int n) {
  int i = blockIdx.x * blockDim.x + threadIdx.x;
  if (i < n) p[i] = 0;
}

__global__ void k_count_deg(const int* __restrict__ dst, int* __restrict__ deg) {
  int e = blockIdx.x * blockDim.x + threadIdx.x;
  if (e < N_EDGES) atomicAdd(&deg[__builtin_nontemporal_load(&dst[e])], 1);
}

__global__ void k_scan_block(const int* __restrict__ deg, int* __restrict__ rowp,
                             int* __restrict__ bsum, float* __restrict__ dis) {
  __shared__ int s[256];
  int tid = threadIdx.x;
  int i = blockIdx.x * 256 + tid;
  int v = (i < N_NODES) ? deg[i] : 0;
  if (i < N_NODES) dis[i] = rsqrtf((float)v + 1.0f);
  s[tid] = v;
  __syncthreads();
  for (int off = 1; off < 256; off <<= 1) {
    int t = (tid >= off) ? s[tid - off] : 0;
    __syncthreads();
    s[tid] += t;
    __syncthreads();
  }
  if (i < N_NODES) rowp[i] = s[tid] - v;
  if (tid == 255) bsum[blockIdx.x] = s[255];
}

__global__ void k_scan_partials(int* __restrict__ bsum, int nb) {
  __shared__ int s[256];
  int tid = threadIdx.x;
  int v = (tid < nb) ? bsum[tid] : 0;
  s[tid] = v;
  __syncthreads();
  for (int off = 1; off < 256; off <<= 1) {
    int t = (tid >= off) ? s[tid - off] : 0;
    __syncthreads();
    s[tid] += t;
    __syncthreads();
  }
  if (tid < nb) bsum[tid] = s[tid] - v;
}

// finish rowp; also init per-partition cursors pcur[p] = rowp[p*256]
__global__ void k_scan_finish(int* __restrict__ rowp, const int* __restrict__ bsum,
                              int* __restrict__ pcur) {
  int i = blockIdx.x * blockDim.x + threadIdx.x;
  if (i < N_NODES) {
    int v = rowp[i] + bsum[i >> 8];
    rowp[i] = v;
    if ((i & 255) == 0) pcur[i >> 8] = v;
  }
  if (i == 0) rowp[N_NODES] = N_EDGES;
}

// Pass A: partition edges by dst>>8; per-block LDS histogram + reservation.
// tmp record = src<<8 | (dst & 255)  (24 bits used)
__global__ __launch_bounds__(256) void k_partA(const int* __restrict__ ei,
                                               int* __restrict__ pcur,
                                               uint* __restrict__ tmp) {
  __shared__ int lcnt[NPART];
  __shared__ int lbase[NPART];
  int tid = threadIdx.x;
  const int per = (N_EDGES + FILL_BLOCKS - 1) / FILL_BLOCKS;  // 6250
  int c0 = blockIdx.x * per;
  int c1 = c0 + per;
  if (c1 > N_EDGES) c1 = N_EDGES;
  for (int i = tid; i < NPART; i += 256) lcnt[i] = 0;
  __syncthreads();
  for (int e = c0 + tid; e < c1; e += 256) {
    int d = __builtin_nontemporal_load(&ei[N_EDGES + e]);
    atomicAdd(&lcnt[d >> 8], 1);
  }
  __syncthreads();
  for (int p = tid; p < NPART; p += 256) lbase[p] = atomicAdd(&pcur[p], lcnt[p]);
  __syncthreads();
  for (int e = c0 + tid; e < c1; e += 256) {
    int s = __builtin_nontemporal_load(&ei[e]);
    int d = __builtin_nontemporal_load(&ei[N_EDGES + e]);
    int pos = atomicAdd(&lbase[d >> 8], 1);
    tmp[pos] = ((uint)s << 8) | (uint)(d & 255);  // grouped runs: L2 merges
  }
}

// Pass B: one block per partition; place records at final CSR positions.
// All writes fall in this block's private window -> single-XCD L2 merge.
__global__ __launch_bounds__(256) void k_partB(const uint* __restrict__ tmp,
                                               const int* __restrict__ rowp,
                                               const float* __restrict__ dis,
                                               uint* __restrict__ edata) {
  __shared__ int cur[256];
  __shared__ float sdis[256];
  int tid = threadIdx.x;
  int p = blockIdx.x;
  int n0 = p << 8;
  {
    int n = n0 + tid;
    cur[tid] = (n < N_NODES) ? rowp[n] : 0;
    sdis[tid] = (n < N_NODES) ? dis[n] : 0.f;
  }
  int base = rowp[n0];
  int endn = n0 + 256;
  if (endn > N_NODES) endn = N_NODES;
  int pend = rowp[endn];
  __syncthreads();
  for (int idx = base + tid; idx < pend; idx += 256) {
    uint t = __builtin_nontemporal_load(&tmp[idx]);
    uint s = t >> 8;
    uint dl = t & 255u;
    int pos = atomicAdd(&cur[dl], 1);
    float coef = dis[s] * sdis[dl];
    edata[pos] = (s << 16) | (uint)f2b(coef);
  }
}

// ---------------- per-layer ----------------

// out16[n][j] = bf16( sum_k bnrelu(in[n][k]) * W[k][j] )
template <bool IN_BF16>
__global__ __launch_bounds__(256) void k_gemm(const void* __restrict__ in,
                                              const float* __restrict__ W,
                                              __hip_bfloat16* __restrict__ out,
                                              float* __restrict__ stats_zero,
                                              const float* __restrict__ stats_in,
                                              const float* __restrict__ gamma,
                                              const float* __restrict__ beta) {
  __shared__ float Al[4][64];
  int tid = threadIdx.x;
  int wid = tid >> 6, f = tid & 63;
  if (blockIdx.x == 0) {
    for (int i = tid; i < 1024; i += 256) stats_zero[i] = 0.0f;
  }
  float Wreg[64];
#pragma unroll
  for (int k = 0; k < 64; ++k) Wreg[k] = W[k * 64 + f];
  float sc = 1.f, sh = 0.f;
  if (stats_in) {
    float s = 0.f, q = 0.f;
#pragma unroll
    for (int c = 0; c < 8; ++c) {
      s += stats_in[c * 128 + f];
      q += stats_in[c * 128 + 64 + f];
    }
    float mu = s * (1.0f / N_NODES);
    float var = q * (1.0f / N_NODES) - mu * mu;
    sc = gamma[f] * rsqrtf(var + BN_EPS);
    sh = beta[f] - mu * sc;
  }
  for (int n = blockIdx.x * 4 + wid; n < N_NODES; n += gridDim.x * 4) {
    float av;
    if (IN_BF16) {
      ushort u = ((const ushort*)in)[(n << 6) + f];
      av = __uint_as_float((uint)u << 16);
    } else {
      av = ((const float*)in)[(n << 6) + f];
    }
    if (stats_in) {
      av = fmaf(av, sc, sh);
      av = av > 0.f ? av : 0.f;
    }
    Al[wid][f] = av;  // same-wave LDS: ordered, no barrier
    float acc = 0.f;
    const float4* arow = (const float4*)Al[wid];
#pragma unroll
    for (int k4 = 0; k4 < 16; ++k4) {
      float4 a = arow[k4];
      acc = fmaf(a.x, Wreg[k4 * 4 + 0], acc);
      acc = fmaf(a.y, Wreg[k4 * 4 + 1], acc);
      acc = fmaf(a.z, Wreg[k4 * 4 + 2], acc);
      acc = fmaf(a.w, Wreg[k4 * 4 + 3], acc);
    }
    out[(n << 6) + f] = __float2bfloat16(acc);  // cached: gather target
  }
}

// group-per-node aggregation: 8-lane group owns one node, lane owns 8 feats.
__global__ __launch_bounds__(256, 4) void k_agg_node(
    const __hip_bfloat16* __restrict__ hW, const float* __restrict__ dis,
    const int* __restrict__ rowp, const uint* __restrict__ edata,
    const float* __restrict__ bias, __hip_bfloat16* __restrict__ act,
    float* __restrict__ stats) {
  __shared__ float sstat[4][2][64];
  int tid = threadIdx.x;
  int wid = tid >> 6, lane = tid & 63;
  int g = lane >> 3, l8 = lane & 7;
  int n = (blockIdx.x * 4 + wid) * 8 + g;  // one node per 8-lane group
  const uint4* hw4 = (const uint4*)hW;
  float pre[8] = {0, 0, 0, 0, 0, 0, 0, 0};
  float sq[8] = {0, 0, 0, 0, 0, 0, 0, 0};
  if (n < N_NODES) {
    int p0 = rowp[n], p1 = rowp[n + 1];
    float acc[8] = {0, 0, 0, 0, 0, 0, 0, 0};
    for (int pb = p0; pb < p1; pb += 8) {
      uint rec = (pb + l8 < p1) ? edata[pb + l8] : 0u;  // 8 recs per group
      uint e[8];
#pragma unroll
      for (int u = 0; u < 8; ++u) e[u] = __shfl(rec, (g << 3) | u, 64);
#pragma unroll
      for (int h = 0; h < 2; ++h) {
        uint4 hv[4];
#pragma unroll
        for (int u = 0; u < 4; ++u) hv[u] = hw4[(e[h * 4 + u] >> 16) * 8 + l8];
#pragma unroll
        for (int u = 0; u < 4; ++u) {
          float wv = blo(e[h * 4 + u]);  // 0 for padded slots
          acc[0] = fmaf(blo(hv[u].x), wv, acc[0]);
          acc[1] = fmaf(bhi(hv[u].x), wv, acc[1]);
          acc[2] = fmaf(blo(hv[u].y), wv, acc[2]);
          acc[3] = fmaf(bhi(hv[u].y), wv, acc[3]);
          acc[4] = fmaf(blo(hv[u].z), wv, acc[4]);
          acc[5] = fmaf(bhi(hv[u].z), wv, acc[5]);
          acc[6] = fmaf(blo(hv[u].w), wv, acc[6]);
          acc[7] = fmaf(bhi(hv[u].w), wv, acc[7]);
        }
      }
    }
    float dn = dis[n];
    float dn2 = dn * dn;
    uint4 hs = hw4[n * 8 + l8];
    const float4* b4 = (const float4*)bias;
    float4 bA = b4[l8 * 2], bB = b4[l8 * 2 + 1];
    pre[0] = fmaf(blo(hs.x), dn2, acc[0]) + bA.x;
    pre[1] = fmaf(bhi(hs.x), dn2, acc[1]) + bA.y;
    pre[2] = fmaf(blo(hs.y), dn2, acc[2]) + bA.z;
    pre[3] = fmaf(bhi(hs.y), dn2, acc[3]) + bA.w;
    pre[4] = fmaf(blo(hs.z), dn2, acc[4]) + bB.x;
    pre[5] = fmaf(bhi(hs.z), dn2, acc[5]) + bB.y;
    pre[6] = fmaf(blo(hs.w), dn2, acc[6]) + bB.z;
    pre[7] = fmaf(bhi(hs.w), dn2, acc[7]) + bB.w;
    uint4 st;
    st.x = (uint)f2b(pre[0]) | ((uint)f2b(pre[1]) << 16);
    st.y = (uint)f2b(pre[2]) | ((uint)f2b(pre[3]) << 16);
    st.z = (uint)f2b(pre[4]) | ((uint)f2b(pre[5]) << 16);
    st.w = (uint)f2b(pre[6]) | ((uint)f2b(pre[7]) << 16);
    ((uint4*)act)[n * 8 + l8] = st;  // group stores contiguous 128B
#pragma unroll
    for (int i = 0; i < 8; ++i) sq[i] = pre[i] * pre[i];
  }
  // one cross-group reduce per wave
#pragma unroll
  for (int off = 8; off < 64; off <<= 1) {
#pragma unroll
    for (int i = 0; i < 8; ++i) {
      pre[i] += __shfl_xor(pre[i], off, 64);
      sq[i] += __shfl_xor(sq[i], off, 64);
    }
  }
  if (g == 0) {
#pragma unroll
    for (int i = 0; i < 8; ++i) {
      sstat[wid][0][l8 * 8 + i] = pre[i];
      sstat[wid][1][l8 * 8 + i] = sq[i];
    }
  }
  __syncthreads();
  if (tid < 128) {
    int which = tid >> 6, f = tid & 63;
    float s = sstat[0][which][f] + sstat[1][which][f] + sstat[2][which][f] +
              sstat[3][which][f];
    atomicAdd(&stats[(blockIdx.x & 7) * 128 + which * 64 + f], s);
  }
}

// ---------------- pool + MLP ----------------

__global__ __launch_bounds__(256) void k_pool(const __hip_bfloat16* __restrict__ act,
                                              const float* __restrict__ stats_in,
                                              const float* __restrict__ gamma,
                                              const float* __restrict__ beta,
                                              float* __restrict__ pooled) {
  int g = blockIdx.x;
  int tid = threadIdx.x;
  int l16 = tid & 15;  // feats 4*l16 .. 4*l16+3
  int r = tid >> 4;    // 16 row-slices
  float sc[4], sh[4];
#pragma unroll
  for (int i = 0; i < 4; ++i) {
    int f = l16 * 4 + i;
    float s = 0.f, q = 0.f;
#pragma unroll
    for (int c = 0; c < 8; ++c) {
      s += stats_in[c * 128 + f];
      q += stats_in[c * 128 + 64 + f];
    }
    float mu = s * (1.0f / N_NODES);
    float var = q * (1.0f / N_NODES) - mu * mu;
    sc[i] = gamma[f] * rsqrtf(var + BN_EPS);
    sh[i] = beta[f] - mu * sc[i];
  }
  int gs = g * N_NODES;
  int start = (gs + 63) >> 6;
  int end = (gs + N_NODES + 63) >> 6;
  float m[4] = {0.f, 0.f, 0.f, 0.f};  // post-ReLU >= 0
  const uint2* a2 = (const uint2*)act;
  for (int n = start + r; n < end; n += 16) {
    uint2 v = a2[n * 16 + l16];
    m[0] = fmaxf(m[0], fmaf(blo(v.x), sc[0], sh[0]));
    m[1] = fmaxf(m[1], fmaf(bhi(v.x), sc[1], sh[1]));
    m[2] = fmaxf(m[2], fmaf(blo(v.y), sc[2], sh[2]));
    m[3] = fmaxf(m[3], fmaf(bhi(v.y), sc[3], sh[3]));
  }
  __shared__ float sm[16][64];
#pragma unroll
  for (int i = 0; i < 4; ++i) sm[r][l16 * 4 + i] = m[i];
  __syncthreads();
  if (tid < 64) {
    float mm = sm[0][tid];
#pragma unroll
    for (int rr = 1; rr < 16; ++rr) mm = fmaxf(mm, sm[rr][tid]);
    pooled[g * 64 + tid] = mm;
  }
}

__global__ __launch_bounds__(256) void k_final(const float* __restrict__ pooled,
                                               const float* __restrict__ w1,
                                               const float* __restrict__ b1,
                                               const float* __restrict__ w2,
                                               const float* __restrict__ b2,
                                               float* __restrict__ out) {
  __shared__ float P[64 * 64];
  __shared__ float Hd[64 * 64];
  int tid = threadIdx.x;
  for (int i = tid; i < 4096; i += 256) P[i] = pooled[i];
  __syncthreads();
  for (int i = tid; i < 4096; i += 256) {
    int g = i >> 6, j = i & 63;
    float acc = b1[j];
#pragma unroll
    for (int k = 0; k < 64; ++k) acc = fmaf(P[g * 64 + k], w1[k * 64 + j], acc);
    Hd[i] = acc > 0.f ? acc : 0.f;
  }
  __syncthreads();
  for (int i = tid; i < 640; i += 256) {
    int g = i / 10, c = i % 10;
    float acc = b2[c];
#pragma unroll
    for (int k = 0; k < 64; ++k) acc = fmaf(Hd[g * 64 + k], w2[k * 10 + c], acc);
    out[i] = acc;
  }
}

// ---------------- launch ----------------

extern "C" void kernel_launch(void* const* d_in, const int* in_sizes, int n_in,
                              void* d_out, int out_size, void* d_ws, size_t ws_size,
                              hipStream_t stream) {
  const float* x = (const float*)d_in[0];
  const int* ei = (const int*)d_in[1];
  const float* W1 = (const float*)d_in[3];
  const float* b1 = (const float*)d_in[4];
  const float* W2 = (const float*)d_in[5];
  const float* b2 = (const float*)d_in[6];
  const float* W3 = (const float*)d_in[7];
  const float* b3 = (const float*)d_in[8];
  const float* gamma = (const float*)d_in[9];
  const float* beta = (const float*)d_in[10];
  const float* l1w = (const float*)d_in[11];
  const float* l1b = (const float*)d_in[12];
  const float* l2w = (const float*)d_in[13];
  const float* l2b = (const float*)d_in[14];
  float* out = (float*)d_out;

  char* ws = (char*)d_ws;
  size_t off = 0;
  auto alloc = [&](size_t bytes) {
    void* p = ws + off;
    off = (off + bytes + 255) & ~(size_t)255;
    return p;
  };
  int* deg = (int*)alloc(N_NODES * 4);
  int* rowp = (int*)alloc((N_NODES + 1) * 4);
  int* pcur = (int*)alloc(NPART * 4);
  int* bsum = (int*)alloc(256 * 4);
  uint* tmp = (uint*)alloc((size_t)N_EDGES * 4);
  uint* edata = (uint*)alloc((size_t)N_EDGES * 4);
  float* dis = (float*)alloc(N_NODES * 4);
  __hip_bfloat16* hW = (__hip_bfloat16*)alloc((size_t)N_NODES * 64 * 2);
  __hip_bfloat16* act = (__hip_bfloat16*)alloc((size_t)N_NODES * 64 * 2);
  float* statsL0 = (float*)alloc(1024 * 4);
  float* statsL1 = (float*)alloc(1024 * 4);
  float* statsL2 = (float*)alloc(1024 * 4);
  float* pooled = (float*)alloc(4096 * 4);

  int nsb = (N_NODES + 255) / 256;   // 196
  int nag = (N_NODES + 31) / 32;     // 1563 blocks, 1 node per 8-lane group

  k_zero<<<nsb, 256, 0, stream>>>(deg, N_NODES);
  k_count_deg<<<(N_EDGES + 255) / 256, 256, 0, stream>>>(ei + N_EDGES, deg);
  k_scan_block<<<nsb, 256, 0, stream>>>(deg, rowp, bsum, dis);
  k_scan_partials<<<1, 256, 0, stream>>>(bsum, nsb);
  k_scan_finish<<<nsb, 256, 0, stream>>>(rowp, bsum, pcur);
  k_partA<<<FILL_BLOCKS, 256, 0, stream>>>(ei, pcur, tmp);
  k_partB<<<NPART, 256, 0, stream>>>(tmp, rowp, dis, edata);

  // layer 1
  k_gemm<false><<<2048, 256, 0, stream>>>(x, W1, hW, statsL0, nullptr, gamma, beta);
  k_agg_node<<<nag, 256, 0, stream>>>(hW, dis, rowp, edata, b1, act, statsL0);
  // layer 2
  k_gemm<true><<<2048, 256, 0, stream>>>(act, W2, hW, statsL1, statsL0, gamma, beta);
  k_agg_node<<<nag, 256, 0, stream>>>(hW, dis, rowp, edata, b2, act, statsL1);
  // layer 3
  k_gemm<true><<<2048, 256, 0, stream>>>(act, W3, hW, statsL2, statsL1, gamma, beta);
  k_agg_node<<<nag, 256, 0, stream>>>(hW, dis, rowp, edata, b3, act, statsL2);

  k_pool<<<N_GRAPHS, 256, 0, stream>>>(act, statsL2, gamma, beta, pooled);
  k_final<<<1, 256, 0, stream>>>(pooled, l1w, l1b, l2w, l2b, out);
}

// Round 13
// 201.628 us; speedup vs baseline: 6.0064x; 1.1184x over previous
//
#include <hip/hip_runtime.h>
#include <hip/hip_bf16.h>

#define N_NODES 50000
#define N_EDGES 800000
#define HID 64
#define N_GRAPHS 64
#define N_CLASSES 10
#define BN_EPS 1e-5f
#define NPART 196          // ceil(50000/256) partitions of 256 dst nodes
#define FILL_BLOCKS 128

typedef unsigned int uint;
typedef unsigned short ushort;

__device__ __forceinline__ float blo(uint u) { return __uint_as_float(u << 16); }
__device__ __forceinline__ float bhi(uint u) { return __uint_as_float(u & 0xffff0000u); }
__device__ __forceinline__ unsigned short f2b(float f) {
  __hip_bfloat16 h = __float2bfloat16(f);
  return *reinterpret_cast<unsigned short*>(&h);
}

// ---------------- build ----------------

__global__ void k_zero_small(int* __restrict__ p, int n) {
  int i = threadIdx.x;
  if (i < n) p[i] = 0;
}

// 196-bin partition histogram (dst>>8) via LDS, merged with global atomics
__global__ __launch_bounds__(256) void k_hist(const int* __restrict__ dst,
                                              int* __restrict__ ghist) {
  __shared__ int l[NPART];
  int tid = threadIdx.x;
  for (int i = tid; i < NPART; i += 256) l[i] = 0;
  __syncthreads();
  const int per = (N_EDGES + FILL_BLOCKS - 1) / FILL_BLOCKS;
  int c0 = blockIdx.x * per;
  int c1 = c0 + per;
  if (c1 > N_EDGES) c1 = N_EDGES;
  for (int e = c0 + tid; e < c1; e += 256)
    atomicAdd(&l[__builtin_nontemporal_load(&dst[e]) >> 8], 1);
  __syncthreads();
  for (int p = tid; p < NPART; p += 256)
    if (l[p]) atomicAdd(&ghist[p], l[p]);
}

// single-block scan over 196 partition counts -> bro (ranges) + pcur (cursors)
__global__ void k_scan196(const int* __restrict__ ghist, int* __restrict__ bro,
                          int* __restrict__ pcur, int* __restrict__ rowp) {
  __shared__ int s[256];
  int tid = threadIdx.x;
  int v = (tid < NPART) ? ghist[tid] : 0;
  s[tid] = v;
  __syncthreads();
  for (int off = 1; off < 256; off <<= 1) {
    int t = (tid >= off) ? s[tid - off] : 0;
    __syncthreads();
    s[tid] += t;
    __syncthreads();
  }
  if (tid < NPART) {
    int e = s[tid] - v;
    bro[tid] = e;
    pcur[tid] = e;
  }
  if (tid == 0) {
    bro[NPART] = N_EDGES;
    rowp[N_NODES] = N_EDGES;
  }
}

// Pass A: partition edges by dst>>8; per-block LDS histogram + reservation.
// tmp record = src<<8 | (dst & 255)  (24 bits used)
__global__ __launch_bounds__(256) void k_partA(const int* __restrict__ ei,
                                               int* __restrict__ pcur,
                                               uint* __restrict__ tmp) {
  __shared__ int lcnt[NPART];
  __shared__ int lbase[NPART];
  int tid = threadIdx.x;
  const int per = (N_EDGES + FILL_BLOCKS - 1) / FILL_BLOCKS;  // 6250
  int c0 = blockIdx.x * per;
  int c1 = c0 + per;
  if (c1 > N_EDGES) c1 = N_EDGES;
  for (int i = tid; i < NPART; i += 256) lcnt[i] = 0;
  __syncthreads();
  for (int e = c0 + tid; e < c1; e += 256) {
    int d = __builtin_nontemporal_load(&ei[N_EDGES + e]);
    atomicAdd(&lcnt[d >> 8], 1);
  }
  __syncthreads();
  for (int p = tid; p < NPART; p += 256) lbase[p] = atomicAdd(&pcur[p], lcnt[p]);
  __syncthreads();
  for (int e = c0 + tid; e < c1; e += 256) {
    int s = __builtin_nontemporal_load(&ei[e]);
    int d = __builtin_nontemporal_load(&ei[N_EDGES + e]);
    int pos = atomicAdd(&lbase[d >> 8], 1);
    tmp[pos] = ((uint)s << 8) | (uint)(d & 255);  // grouped runs: L2 merges
  }
}

// Pass B: one block per partition. Counts per-node degree (LDS), derives
// dis + rowp for its 256 nodes, then places ushort src records in final
// CSR order. All writes block-private -> fully merged.
__global__ __launch_bounds__(256) void k_partB(const uint* __restrict__ tmp,
                                               const int* __restrict__ bro,
                                               float* __restrict__ dis,
                                               int* __restrict__ rowp,
                                               ushort* __restrict__ eus) {
  __shared__ int cnt[256];
  __shared__ int s[256];
  __shared__ int cur[256];
  int tid = threadIdx.x;
  int p = blockIdx.x;
  int base = bro[p], pend = bro[p + 1];
  cnt[tid] = 0;
  __syncthreads();
  for (int idx = base + tid; idx < pend; idx += 256)
    atomicAdd(&cnt[__builtin_nontemporal_load(&tmp[idx]) & 255u], 1);
  __syncthreads();
  int deg = cnt[tid];
  int n = (p << 8) + tid;
  if (n < N_NODES) dis[n] = rsqrtf((float)deg + 1.0f);
  // exclusive scan of deg over 256
  s[tid] = deg;
  __syncthreads();
  for (int off = 1; off < 256; off <<= 1) {
    int t = (tid >= off) ? s[tid - off] : 0;
    __syncthreads();
    s[tid] += t;
    __syncthreads();
  }
  int start = base + s[tid] - deg;
  if (n < N_NODES) rowp[n] = start;
  cur[tid] = start;
  __syncthreads();
  for (int idx = base + tid; idx < pend; idx += 256) {
    uint t = __builtin_nontemporal_load(&tmp[idx]);
    int pos = atomicAdd(&cur[t & 255u], 1);
    eus[pos] = (ushort)(t >> 8);
  }
}

// ---------------- per-layer ----------------

// out16[n][j] = bf16( sum_k bnrelu(in[n][k]) * W[k][j] )
template <bool IN_BF16>
__global__ __launch_bounds__(256) void k_gemm(const void* __restrict__ in,
                                              const float* __restrict__ W,
                                              __hip_bfloat16* __restrict__ out,
                                              float* __restrict__ stats_zero,
                                              const float* __restrict__ stats_in,
                                              const float* __restrict__ gamma,
                                              const float* __restrict__ beta) {
  __shared__ float Al[4][64];
  int tid = threadIdx.x;
  int wid = tid >> 6, f = tid & 63;
  if (blockIdx.x == 0) {
    for (int i = tid; i < 1024; i += 256) stats_zero[i] = 0.0f;
  }
  float Wreg[64];
#pragma unroll
  for (int k = 0; k < 64; ++k) Wreg[k] = W[k * 64 + f];
  float sc = 1.f, sh = 0.f;
  if (stats_in) {
    float s = 0.f, q = 0.f;
#pragma unroll
    for (int c = 0; c < 8; ++c) {
      s += stats_in[c * 128 + f];
      q += stats_in[c * 128 + 64 + f];
    }
    float mu = s * (1.0f / N_NODES);
    float var = q * (1.0f / N_NODES) - mu * mu;
    sc = gamma[f] * rsqrtf(var + BN_EPS);
    sh = beta[f] - mu * sc;
  }
  for (int n = blockIdx.x * 4 + wid; n < N_NODES; n += gridDim.x * 4) {
    float av;
    if (IN_BF16) {
      ushort u = ((const ushort*)in)[(n << 6) + f];
      av = __uint_as_float((uint)u << 16);
    } else {
      av = ((const float*)in)[(n << 6) + f];
    }
    if (stats_in) {
      av = fmaf(av, sc, sh);
      av = av > 0.f ? av : 0.f;
    }
    Al[wid][f] = av;  // same-wave LDS: ordered, no barrier
    float acc = 0.f;
    const float4* arow = (const float4*)Al[wid];
#pragma unroll
    for (int k4 = 0; k4 < 16; ++k4) {
      float4 a = arow[k4];
      acc = fmaf(a.x, Wreg[k4 * 4 + 0], acc);
      acc = fmaf(a.y, Wreg[k4 * 4 + 1], acc);
      acc = fmaf(a.z, Wreg[k4 * 4 + 2], acc);
      acc = fmaf(a.w, Wreg[k4 * 4 + 3], acc);
    }
    out[(n << 6) + f] = __float2bfloat16(acc);  // cached: gather target
  }
}

// group-per-node aggregation: 8-lane group owns one node, lane owns 8 feats.
// ushort src records; coef = dis[src]*dis[n] rebuilt in-flight (dis L2-hot).
__global__ __launch_bounds__(256, 4) void k_agg_node(
    const __hip_bfloat16* __restrict__ hW, const float* __restrict__ dis,
    const int* __restrict__ rowp, const ushort* __restrict__ eus,
    const float* __restrict__ bias, __hip_bfloat16* __restrict__ act,
    float* __restrict__ stats) {
  __shared__ float sstat[4][2][64];
  int tid = threadIdx.x;
  int wid = tid >> 6, lane = tid & 63;
  int g = lane >> 3, l8 = lane & 7;
  int n = (blockIdx.x * 4 + wid) * 8 + g;  // one node per 8-lane group
  const uint4* hw4 = (const uint4*)hW;
  float pre[8] = {0, 0, 0, 0, 0, 0, 0, 0};
  float sq[8] = {0, 0, 0, 0, 0, 0, 0, 0};
  if (n < N_NODES) {
    int p0 = rowp[n], p1 = rowp[n + 1];
    float dn = dis[n];
    float acc[8] = {0, 0, 0, 0, 0, 0, 0, 0};
    for (int pb = p0; pb < p1; pb += 8) {
      int idx = pb + l8;
      if (idx >= N_EDGES) idx = N_EDGES - 1;   // clamp: src stays valid
      uint rs = eus[idx];                       // group's 8 records (16B)
#pragma unroll
      for (int h = 0; h < 2; ++h) {
        uint e4[4];
        float ds4[4];
        uint4 hv[4];
#pragma unroll
        for (int u = 0; u < 4; ++u) e4[u] = __shfl(rs, (g << 3) | (h * 4 + u), 64);
#pragma unroll
        for (int u = 0; u < 4; ++u) {
          hv[u] = hw4[e4[u] * 8 + l8];  // 4 rows in flight
          ds4[u] = dis[e4[u]];          // L2-hot, overlaps gather
        }
#pragma unroll
        for (int u = 0; u < 4; ++u) {
          float wv = (pb + h * 4 + u < p1) ? ds4[u] * dn : 0.f;
          acc[0] = fmaf(blo(hv[u].x), wv, acc[0]);
          acc[1] = fmaf(bhi(hv[u].x), wv, acc[1]);
          acc[2] = fmaf(blo(hv[u].y), wv, acc[2]);
          acc[3] = fmaf(bhi(hv[u].y), wv, acc[3]);
          acc[4] = fmaf(blo(hv[u].z), wv, acc[4]);
          acc[5] = fmaf(bhi(hv[u].z), wv, acc[5]);
          acc[6] = fmaf(blo(hv[u].w), wv, acc[6]);
          acc[7] = fmaf(bhi(hv[u].w), wv, acc[7]);
        }
      }
    }
    float dn2 = dn * dn;
    uint4 hs = hw4[n * 8 + l8];
    const float4* b4 = (const float4*)bias;
    float4 bA = b4[l8 * 2], bB = b4[l8 * 2 + 1];
    pre[0] = fmaf(blo(hs.x), dn2, acc[0]) + bA.x;
    pre[1] = fmaf(bhi(hs.x), dn2, acc[1]) + bA.y;
    pre[2] = fmaf(blo(hs.y), dn2, acc[2]) + bA.z;
    pre[3] = fmaf(bhi(hs.y), dn2, acc[3]) + bA.w;
    pre[4] = fmaf(blo(hs.z), dn2, acc[4]) + bB.x;
    pre[5] = fmaf(bhi(hs.z), dn2, acc[5]) + bB.y;
    pre[6] = fmaf(blo(hs.w), dn2, acc[6]) + bB.z;
    pre[7] = fmaf(bhi(hs.w), dn2, acc[7]) + bB.w;
    uint4 st;
    st.x = (uint)f2b(pre[0]) | ((uint)f2b(pre[1]) << 16);
    st.y = (uint)f2b(pre[2]) | ((uint)f2b(pre[3]) << 16);
    st.z = (uint)f2b(pre[4]) | ((uint)f2b(pre[5]) << 16);
    st.w = (uint)f2b(pre[6]) | ((uint)f2b(pre[7]) << 16);
    ((uint4*)act)[n * 8 + l8] = st;  // group stores contiguous 128B
#pragma unroll
    for (int i = 0; i < 8; ++i) sq[i] = pre[i] * pre[i];
  }
  // one cross-group reduce per wave
#pragma unroll
  for (int off = 8; off < 64; off <<= 1) {
#pragma unroll
    for (int i = 0; i < 8; ++i) {
      pre[i] += __shfl_xor(pre[i], off, 64);
      sq[i] += __shfl_xor(sq[i], off, 64);
    }
  }
  if (g == 0) {
#pragma unroll
    for (int i = 0; i < 8; ++i) {
      sstat[wid][0][l8 * 8 + i] = pre[i];
      sstat[wid][1][l8 * 8 + i] = sq[i];
    }
  }
  __syncthreads();
  if (tid < 128) {
    int which = tid >> 6, f = tid & 63;
    float s = sstat[0][which][f] + sstat[1][which][f] + sstat[2][which][f] +
              sstat[3][which][f];
    atomicAdd(&stats[(blockIdx.x & 7) * 128 + which * 64 + f], s);
  }
}

// ---------------- pool + MLP ----------------

__global__ __launch_bounds__(256) void k_pool(const __hip_bfloat16* __restrict__ act,
                                              const float* __restrict__ stats_in,
                                              const float* __restrict__ gamma,
                                              const float* __restrict__ beta,
                                              float* __restrict__ pooled) {
  int g = blockIdx.x;
  int tid = threadIdx.x;
  int l16 = tid & 15;  // feats 4*l16 .. 4*l16+3
  int r = tid >> 4;    // 16 row-slices
  float sc[4], sh[4];
#pragma unroll
  for (int i = 0; i < 4; ++i) {
    int f = l16 * 4 + i;
    float s = 0.f, q = 0.f;
#pragma unroll
    for (int c = 0; c < 8; ++c) {
      s += stats_in[c * 128 + f];
      q += stats_in[c * 128 + 64 + f];
    }
    float mu = s * (1.0f / N_NODES);
    float var = q * (1.0f / N_NODES) - mu * mu;
    sc[i] = gamma[f] * rsqrtf(var + BN_EPS);
    sh[i] = beta[f] - mu * sc[i];
  }
  int gs = g * N_NODES;
  int start = (gs + 63) >> 6;
  int end = (gs + N_NODES + 63) >> 6;
  float m[4] = {0.f, 0.f, 0.f, 0.f};  // post-ReLU >= 0
  const uint2* a2 = (const uint2*)act;
  for (int n = start + r; n < end; n += 16) {
    uint2 v = a2[n * 16 + l16];
    m[0] = fmaxf(m[0], fmaf(blo(v.x), sc[0], sh[0]));
    m[1] = fmaxf(m[1], fmaf(bhi(v.x), sc[1], sh[1]));
    m[2] = fmaxf(m[2], fmaf(blo(v.y), sc[2], sh[2]));
    m[3] = fmaxf(m[3], fmaf(bhi(v.y), sc[3], sh[3]));
  }
  __shared__ float sm[16][64];
#pragma unroll
  for (int i = 0; i < 4; ++i) sm[r][l16 * 4 + i] = m[i];
  __syncthreads();
  if (tid < 64) {
    float mm = sm[0][tid];
#pragma unroll
    for (int rr = 1; rr < 16; ++rr) mm = fmaxf(mm, sm[rr][tid]);
    pooled[g * 64 + tid] = mm;
  }
}

__global__ __launch_bounds__(256) void k_final(const float* __restrict__ pooled,
                                               const float* __restrict__ w1,
                                               const float* __restrict__ b1,
                                               const float* __restrict__ w2,
                                               const float* __restrict__ b2,
                                               float* __restrict__ out) {
  __shared__ float P[64 * 64];
  __shared__ float Hd[64 * 64];
  int tid = threadIdx.x;
  for (int i = tid; i < 4096; i += 256) P[i] = pooled[i];
  __syncthreads();
  for (int i = tid; i < 4096; i += 256) {
    int g = i >> 6, j = i & 63;
    float acc = b1[j];
#pragma unroll
    for (int k = 0; k < 64; ++k) acc = fmaf(P[g * 64 + k], w1[k * 64 + j], acc);
    Hd[i] = acc > 0.f ? acc : 0.f;
  }
  __syncthreads();
  for (int i = tid; i < 640; i += 256) {
    int g = i / 10, c = i % 10;
    float acc = b2[c];
#pragma unroll
    for (int k = 0; k < 64; ++k) acc = fmaf(Hd[g * 64 + k], w2[k * 10 + c], acc);
    out[i] = acc;
  }
}

// ---------------- launch ----------------

extern "C" void kernel_launch(void* const* d_in, const int* in_sizes, int n_in,
                              void* d_out, int out_size, void* d_ws, size_t ws_size,
                              hipStream_t stream) {
  const float* x = (const float*)d_in[0];
  const int* ei = (const int*)d_in[1];
  const float* W1 = (const float*)d_in[3];
  const float* b1 = (const float*)d_in[4];
  const float* W2 = (const float*)d_in[5];
  const float* b2 = (const float*)d_in[6];
  const float* W3 = (const float*)d_in[7];
  const float* b3 = (const float*)d_in[8];
  const float* gamma = (const float*)d_in[9];
  const float* beta = (const float*)d_in[10];
  const float* l1w = (const float*)d_in[11];
  const float* l1b = (const float*)d_in[12];
  const float* l2w = (const float*)d_in[13];
  const float* l2b = (const float*)d_in[14];
  float* out = (float*)d_out;

  char* ws = (char*)d_ws;
  size_t off = 0;
  auto alloc = [&](size_t bytes) {
    void* p = ws + off;
    off = (off + bytes + 255) & ~(size_t)255;
    return p;
  };
  int* ghist = (int*)alloc(NPART * 4);
  int* bro = (int*)alloc((NPART + 1) * 4);
  int* pcur = (int*)alloc(NPART * 4);
  int* rowp = (int*)alloc((N_NODES + 1) * 4);
  uint* tmp = (uint*)alloc((size_t)N_EDGES * 4);
  ushort* eus = (ushort*)alloc((size_t)N_EDGES * 2 + 512);
  float* dis = (float*)alloc(N_NODES * 4);
  __hip_bfloat16* hW = (__hip_bfloat16*)alloc((size_t)N_NODES * 64 * 2);
  __hip_bfloat16* act = (__hip_bfloat16*)alloc((size_t)N_NODES * 64 * 2);
  float* statsL0 = (float*)alloc(1024 * 4);
  float* statsL1 = (float*)alloc(1024 * 4);
  float* statsL2 = (float*)alloc(1024 * 4);
  float* pooled = (float*)alloc(4096 * 4);

  int nag = (N_NODES + 31) / 32;  // 1563 blocks, 1 node per 8-lane group

  k_zero_small<<<1, 256, 0, stream>>>(ghist, NPART);
  k_hist<<<FILL_BLOCKS, 256, 0, stream>>>(ei + N_EDGES, ghist);
  k_scan196<<<1, 256, 0, stream>>>(ghist, bro, pcur, rowp);
  k_partA<<<FILL_BLOCKS, 256, 0, stream>>>(ei, pcur, tmp);
  k_partB<<<NPART, 256, 0, stream>>>(tmp, bro, dis, rowp, eus);

  // layer 1
  k_gemm<false><<<2048, 256, 0, stream>>>(x, W1, hW, statsL0, nullptr, gamma, beta);
  k_agg_node<<<nag, 256, 0, stream>>>(hW, dis, rowp, eus, b1, act, statsL0);
  // layer 2
  k_gemm<true><<<2048, 256, 0, stream>>>(act, W2, hW, statsL1, statsL0, gamma, beta);
  k_agg_node<<<nag, 256, 0, stream>>>(hW, dis, rowp, eus, b2, act, statsL1);
  // layer 3
  k_gemm<true><<<2048, 256, 0, stream>>>(act, W3, hW, statsL2, statsL1, gamma, beta);
  k_agg_node<<<nag, 256, 0, stream>>>(hW, dis, rowp, eus, b3, act, statsL2);

  k_pool<<<N_GRAPHS, 256, 0, stream>>>(act, statsL2, gamma, beta, pooled);
  k_final<<<1, 256, 0, stream>>>(pooled, l1w, l1b, l2w, l2b, out);
}

// Round 14
// 200.841 us; speedup vs baseline: 6.0299x; 1.0039x over previous
//
#include <hip/hip_runtime.h>
#include <hip/hip_bf16.h>

#define N_NODES 50000
#define N_EDGES 800000
#define HID 64
#define N_GRAPHS 64
#define N_CLASSES 10
#define BN_EPS 1e-5f
#define NPART 196          // ceil(50000/256) partitions of 256 dst nodes
#define FILL_BLOCKS 128

typedef unsigned int uint;
typedef unsigned short ushort;

__device__ __forceinline__ float blo(uint u) { return __uint_as_float(u << 16); }
__device__ __forceinline__ float bhi(uint u) { return __uint_as_float(u & 0xffff0000u); }
__device__ __forceinline__ unsigned short f2b(float f) {
  __hip_bfloat16 h = __float2bfloat16(f);
  return *reinterpret_cast<unsigned short*>(&h);
}

// ---------------- build ----------------

__global__ void k_zero_small(int* __restrict__ p, int n) {
  int i = threadIdx.x;
  if (i < n) p[i] = 0;
}

// 196-bin partition histogram (dst>>8) via LDS, merged with global atomics
__global__ __launch_bounds__(256) void k_hist(const int* __restrict__ dst,
                                              int* __restrict__ ghist) {
  __shared__ int l[NPART];
  int tid = threadIdx.x;
  for (int i = tid; i < NPART; i += 256) l[i] = 0;
  __syncthreads();
  const int per = (N_EDGES + FILL_BLOCKS - 1) / FILL_BLOCKS;
  int c0 = blockIdx.x * per;
  int c1 = c0 + per;
  if (c1 > N_EDGES) c1 = N_EDGES;
  for (int e = c0 + tid; e < c1; e += 256)
    atomicAdd(&l[__builtin_nontemporal_load(&dst[e]) >> 8], 1);
  __syncthreads();
  for (int p = tid; p < NPART; p += 256)
    if (l[p]) atomicAdd(&ghist[p], l[p]);
}

// single-block scan over 196 partition counts -> bro (ranges) + pcur (cursors)
__global__ void k_scan196(const int* __restrict__ ghist, int* __restrict__ bro,
                          int* __restrict__ pcur, int* __restrict__ rowp) {
  __shared__ int s[256];
  int tid = threadIdx.x;
  int v = (tid < NPART) ? ghist[tid] : 0;
  s[tid] = v;
  __syncthreads();
  for (int off = 1; off < 256; off <<= 1) {
    int t = (tid >= off) ? s[tid - off] : 0;
    __syncthreads();
    s[tid] += t;
    __syncthreads();
  }
  if (tid < NPART) {
    int e = s[tid] - v;
    bro[tid] = e;
    pcur[tid] = e;
  }
  if (tid == 0) {
    bro[NPART] = N_EDGES;
    rowp[N_NODES] = N_EDGES;
  }
}

// Pass A: partition edges by dst>>8; per-block LDS histogram + reservation.
// tmp record = src<<8 | (dst & 255)  (24 bits used)
__global__ __launch_bounds__(256) void k_partA(const int* __restrict__ ei,
                                               int* __restrict__ pcur,
                                               uint* __restrict__ tmp) {
  __shared__ int lcnt[NPART];
  __shared__ int lbase[NPART];
  int tid = threadIdx.x;
  const int per = (N_EDGES + FILL_BLOCKS - 1) / FILL_BLOCKS;  // 6250
  int c0 = blockIdx.x * per;
  int c1 = c0 + per;
  if (c1 > N_EDGES) c1 = N_EDGES;
  for (int i = tid; i < NPART; i += 256) lcnt[i] = 0;
  __syncthreads();
  for (int e = c0 + tid; e < c1; e += 256) {
    int d = __builtin_nontemporal_load(&ei[N_EDGES + e]);
    atomicAdd(&lcnt[d >> 8], 1);
  }
  __syncthreads();
  for (int p = tid; p < NPART; p += 256) lbase[p] = atomicAdd(&pcur[p], lcnt[p]);
  __syncthreads();
  for (int e = c0 + tid; e < c1; e += 256) {
    int s = __builtin_nontemporal_load(&ei[e]);
    int d = __builtin_nontemporal_load(&ei[N_EDGES + e]);
    int pos = atomicAdd(&lbase[d >> 8], 1);
    tmp[pos] = ((uint)s << 8) | (uint)(d & 255);  // grouped runs: L2 merges
  }
}

// Pass B: one block per partition. Counts per-node degree (LDS), derives
// dis + rowp for its 256 nodes, then places ushort src records in final
// CSR order. All writes block-private -> fully merged.
__global__ __launch_bounds__(256) void k_partB(const uint* __restrict__ tmp,
                                               const int* __restrict__ bro,
                                               float* __restrict__ dis,
                                               int* __restrict__ rowp,
                                               ushort* __restrict__ eus) {
  __shared__ int cnt[256];
  __shared__ int s[256];
  __shared__ int cur[256];
  int tid = threadIdx.x;
  int p = blockIdx.x;
  int base = bro[p], pend = bro[p + 1];
  cnt[tid] = 0;
  __syncthreads();
  for (int idx = base + tid; idx < pend; idx += 256)
    atomicAdd(&cnt[__builtin_nontemporal_load(&tmp[idx]) & 255u], 1);
  __syncthreads();
  int deg = cnt[tid];
  int n = (p << 8) + tid;
  if (n < N_NODES) dis[n] = rsqrtf((float)deg + 1.0f);
  // exclusive scan of deg over 256
  s[tid] = deg;
  __syncthreads();
  for (int off = 1; off < 256; off <<= 1) {
    int t = (tid >= off) ? s[tid - off] : 0;
    __syncthreads();
    s[tid] += t;
    __syncthreads();
  }
  int start = base + s[tid] - deg;
  if (n < N_NODES) rowp[n] = start;
  cur[tid] = start;
  __syncthreads();
  for (int idx = base + tid; idx < pend; idx += 256) {
    uint t = __builtin_nontemporal_load(&tmp[idx]);
    int pos = atomicAdd(&cur[t & 255u], 1);
    eus[pos] = (ushort)(t >> 8);
  }
}

// ---------------- per-layer ----------------

// out16[n][j] = bf16( sum_k bnrelu(in[n][k]) * W[k][j] )
template <bool IN_BF16>
__global__ __launch_bounds__(256) void k_gemm(const void* __restrict__ in,
                                              const float* __restrict__ W,
                                              __hip_bfloat16* __restrict__ out,
                                              float* __restrict__ stats_zero,
                                              const float* __restrict__ stats_in,
                                              const float* __restrict__ gamma,
                                              const float* __restrict__ beta) {
  __shared__ float Al[4][64];
  int tid = threadIdx.x;
  int wid = tid >> 6, f = tid & 63;
  if (blockIdx.x == 0) {
    for (int i = tid; i < 1024; i += 256) stats_zero[i] = 0.0f;
  }
  float Wreg[64];
#pragma unroll
  for (int k = 0; k < 64; ++k) Wreg[k] = W[k * 64 + f];
  float sc = 1.f, sh = 0.f;
  if (stats_in) {
    float s = 0.f, q = 0.f;
#pragma unroll
    for (int c = 0; c < 8; ++c) {
      s += stats_in[c * 128 + f];
      q += stats_in[c * 128 + 64 + f];
    }
    float mu = s * (1.0f / N_NODES);
    float var = q * (1.0f / N_NODES) - mu * mu;
    sc = gamma[f] * rsqrtf(var + BN_EPS);
    sh = beta[f] - mu * sc;
  }
  for (int n = blockIdx.x * 4 + wid; n < N_NODES; n += gridDim.x * 4) {
    float av;
    if (IN_BF16) {
      ushort u = ((const ushort*)in)[(n << 6) + f];
      av = __uint_as_float((uint)u << 16);
    } else {
      av = ((const float*)in)[(n << 6) + f];
    }
    if (stats_in) {
      av = fmaf(av, sc, sh);
      av = av > 0.f ? av : 0.f;
    }
    Al[wid][f] = av;  // same-wave LDS: ordered, no barrier
    float acc = 0.f;
    const float4* arow = (const float4*)Al[wid];
#pragma unroll
    for (int k4 = 0; k4 < 16; ++k4) {
      float4 a = arow[k4];
      acc = fmaf(a.x, Wreg[k4 * 4 + 0], acc);
      acc = fmaf(a.y, Wreg[k4 * 4 + 1], acc);
      acc = fmaf(a.z, Wreg[k4 * 4 + 2], acc);
      acc = fmaf(a.w, Wreg[k4 * 4 + 3], acc);
    }
    out[(n << 6) + f] = __float2bfloat16(acc);  // cached: gather target
  }
}

// group-per-node aggregation: 8-lane group owns one node, lane owns 8 feats.
// ushort src records; coef = dis[src]*dis[n] rebuilt in-flight (dis L2-hot).
// Edge-batch records are software-pipelined: next batch's load overlaps the
// current batch's gathers.
__global__ __launch_bounds__(256, 4) void k_agg_node(
    const __hip_bfloat16* __restrict__ hW, const float* __restrict__ dis,
    const int* __restrict__ rowp, const ushort* __restrict__ eus,
    const float* __restrict__ bias, __hip_bfloat16* __restrict__ act,
    float* __restrict__ stats) {
  __shared__ float sstat[4][2][64];
  int tid = threadIdx.x;
  int wid = tid >> 6, lane = tid & 63;
  int g = lane >> 3, l8 = lane & 7;
  int n = (blockIdx.x * 4 + wid) * 8 + g;  // one node per 8-lane group
  const uint4* hw4 = (const uint4*)hW;
  float pre[8] = {0, 0, 0, 0, 0, 0, 0, 0};
  float sq[8] = {0, 0, 0, 0, 0, 0, 0, 0};
  if (n < N_NODES) {
    int p0 = rowp[n], p1 = rowp[n + 1];
    float dn = dis[n];
    uint4 hs = hw4[n * 8 + l8];  // hoisted self row: overlaps edge loop
    float acc[8] = {0, 0, 0, 0, 0, 0, 0, 0};
    uint rs = 0u;
    if (p0 < p1) {
      int i0 = p0 + l8;
      rs = eus[i0 < N_EDGES ? i0 : N_EDGES - 1];
    }
    for (int pb = p0; pb < p1; pb += 8) {
      // prefetch next batch's records: overlaps this batch's gathers
      uint rs_nx = 0u;
      if (pb + 8 < p1) {
        int i1 = pb + 8 + l8;
        rs_nx = eus[i1 < N_EDGES ? i1 : N_EDGES - 1];
      }
#pragma unroll
      for (int h = 0; h < 2; ++h) {
        uint e4[4];
        float ds4[4];
        uint4 hv[4];
#pragma unroll
        for (int u = 0; u < 4; ++u) e4[u] = __shfl(rs, (g << 3) | (h * 4 + u), 64);
#pragma unroll
        for (int u = 0; u < 4; ++u) {
          hv[u] = hw4[e4[u] * 8 + l8];  // 4 rows in flight
          ds4[u] = dis[e4[u]];          // L2-hot, co-issues with gather
        }
#pragma unroll
        for (int u = 0; u < 4; ++u) {
          float wv = (pb + h * 4 + u < p1) ? ds4[u] * dn : 0.f;
          acc[0] = fmaf(blo(hv[u].x), wv, acc[0]);
          acc[1] = fmaf(bhi(hv[u].x), wv, acc[1]);
          acc[2] = fmaf(blo(hv[u].y), wv, acc[2]);
          acc[3] = fmaf(bhi(hv[u].y), wv, acc[3]);
          acc[4] = fmaf(blo(hv[u].z), wv, acc[4]);
          acc[5] = fmaf(bhi(hv[u].z), wv, acc[5]);
          acc[6] = fmaf(blo(hv[u].w), wv, acc[6]);
          acc[7] = fmaf(bhi(hv[u].w), wv, acc[7]);
        }
      }
      rs = rs_nx;
    }
    float dn2 = dn * dn;
    const float4* b4 = (const float4*)bias;
    float4 bA = b4[l8 * 2], bB = b4[l8 * 2 + 1];
    pre[0] = fmaf(blo(hs.x), dn2, acc[0]) + bA.x;
    pre[1] = fmaf(bhi(hs.x), dn2, acc[1]) + bA.y;
    pre[2] = fmaf(blo(hs.y), dn2, acc[2]) + bA.z;
    pre[3] = fmaf(bhi(hs.y), dn2, acc[3]) + bA.w;
    pre[4] = fmaf(blo(hs.z), dn2, acc[4]) + bB.x;
    pre[5] = fmaf(bhi(hs.z), dn2, acc[5]) + bB.y;
    pre[6] = fmaf(blo(hs.w), dn2, acc[6]) + bB.z;
    pre[7] = fmaf(bhi(hs.w), dn2, acc[7]) + bB.w;
    uint4 st;
    st.x = (uint)f2b(pre[0]) | ((uint)f2b(pre[1]) << 16);
    st.y = (uint)f2b(pre[2]) | ((uint)f2b(pre[3]) << 16);
    st.z = (uint)f2b(pre[4]) | ((uint)f2b(pre[5]) << 16);
    st.w = (uint)f2b(pre[6]) | ((uint)f2b(pre[7]) << 16);
    ((uint4*)act)[n * 8 + l8] = st;  // group stores contiguous 128B
#pragma unroll
    for (int i = 0; i < 8; ++i) sq[i] = pre[i] * pre[i];
  }
  // one cross-group reduce per wave
#pragma unroll
  for (int off = 8; off < 64; off <<= 1) {
#pragma unroll
    for (int i = 0; i < 8; ++i) {
      pre[i] += __shfl_xor(pre[i], off, 64);
      sq[i] += __shfl_xor(sq[i], off, 64);
    }
  }
  if (g == 0) {
#pragma unroll
    for (int i = 0; i < 8; ++i) {
      sstat[wid][0][l8 * 8 + i] = pre[i];
      sstat[wid][1][l8 * 8 + i] = sq[i];
    }
  }
  __syncthreads();
  if (tid < 128) {
    int which = tid >> 6, f = tid & 63;
    float s = sstat[0][which][f] + sstat[1][which][f] + sstat[2][which][f] +
              sstat[3][which][f];
    atomicAdd(&stats[(blockIdx.x & 7) * 128 + which * 64 + f], s);
  }
}

// ---------------- pool + MLP ----------------

__global__ __launch_bounds__(256) void k_pool(const __hip_bfloat16* __restrict__ act,
                                              const float* __restrict__ stats_in,
                                              const float* __restrict__ gamma,
                                              const float* __restrict__ beta,
                                              float* __restrict__ pooled) {
  int g = blockIdx.x;
  int tid = threadIdx.x;
  int l16 = tid & 15;  // feats 4*l16 .. 4*l16+3
  int r = tid >> 4;    // 16 row-slices
  float sc[4], sh[4];
#pragma unroll
  for (int i = 0; i < 4; ++i) {
    int f = l16 * 4 + i;
    float s = 0.f, q = 0.f;
#pragma unroll
    for (int c = 0; c < 8; ++c) {
      s += stats_in[c * 128 + f];
      q += stats_in[c * 128 + 64 + f];
    }
    float mu = s * (1.0f / N_NODES);
    float var = q * (1.0f / N_NODES) - mu * mu;
    sc[i] = gamma[f] * rsqrtf(var + BN_EPS);
    sh[i] = beta[f] - mu * sc[i];
  }
  int gs = g * N_NODES;
  int start = (gs + 63) >> 6;
  int end = (gs + N_NODES + 63) >> 6;
  float m[4] = {0.f, 0.f, 0.f, 0.f};  // post-ReLU >= 0
  const uint2* a2 = (const uint2*)act;
  for (int n = start + r; n < end; n += 16) {
    uint2 v = a2[n * 16 + l16];
    m[0] = fmaxf(m[0], fmaf(blo(v.x), sc[0], sh[0]));
    m[1] = fmaxf(m[1], fmaf(bhi(v.x), sc[1], sh[1]));
    m[2] = fmaxf(m[2], fmaf(blo(v.y), sc[2], sh[2]));
    m[3] = fmaxf(m[3], fmaf(bhi(v.y), sc[3], sh[3]));
  }
  __shared__ float sm[16][64];
#pragma unroll
  for (int i = 0; i < 4; ++i) sm[r][l16 * 4 + i] = m[i];
  __syncthreads();
  if (tid < 64) {
    float mm = sm[0][tid];
#pragma unroll
    for (int rr = 1; rr < 16; ++rr) mm = fmaxf(mm, sm[rr][tid]);
    pooled[g * 64 + tid] = mm;
  }
}

__global__ __launch_bounds__(256) void k_final(const float* __restrict__ pooled,
                                               const float* __restrict__ w1,
                                               const float* __restrict__ b1,
                                               const float* __restrict__ w2,
                                               const float* __restrict__ b2,
                                               float* __restrict__ out) {
  __shared__ float P[64 * 64];
  __shared__ float Hd[64 * 64];
  int tid = threadIdx.x;
  for (int i = tid; i < 4096; i += 256) P[i] = pooled[i];
  __syncthreads();
  for (int i = tid; i < 4096; i += 256) {
    int g = i >> 6, j = i & 63;
    float acc = b1[j];
#pragma unroll
    for (int k = 0; k < 64; ++k) acc = fmaf(P[g * 64 + k], w1[k * 64 + j], acc);
    Hd[i] = acc > 0.f ? acc : 0.f;
  }
  __syncthreads();
  for (int i = tid; i < 640; i += 256) {
    int g = i / 10, c = i % 10;
    float acc = b2[c];
#pragma unroll
    for (int k = 0; k < 64; ++k) acc = fmaf(Hd[g * 64 + k], w2[k * 10 + c], acc);
    out[i] = acc;
  }
}

// ---------------- launch ----------------

extern "C" void kernel_launch(void* const* d_in, const int* in_sizes, int n_in,
                              void* d_out, int out_size, void* d_ws, size_t ws_size,
                              hipStream_t stream) {
  const float* x = (const float*)d_in[0];
  const int* ei = (const int*)d_in[1];
  const float* W1 = (const float*)d_in[3];
  const float* b1 = (const float*)d_in[4];
  const float* W2 = (const float*)d_in[5];
  const float* b2 = (const float*)d_in[6];
  const float* W3 = (const float*)d_in[7];
  const float* b3 = (const float*)d_in[8];
  const float* gamma = (const float*)d_in[9];
  const float* beta = (const float*)d_in[10];
  const float* l1w = (const float*)d_in[11];
  const float* l1b = (const float*)d_in[12];
  const float* l2w = (const float*)d_in[13];
  const float* l2b = (const float*)d_in[14];
  float* out = (float*)d_out;

  char* ws = (char*)d_ws;
  size_t off = 0;
  auto alloc = [&](size_t bytes) {
    void* p = ws + off;
    off = (off + bytes + 255) & ~(size_t)255;
    return p;
  };
  int* ghist = (int*)alloc(NPART * 4);
  int* bro = (int*)alloc((NPART + 1) * 4);
  int* pcur = (int*)alloc(NPART * 4);
  int* rowp = (int*)alloc((N_NODES + 1) * 4);
  uint* tmp = (uint*)alloc((size_t)N_EDGES * 4);
  ushort* eus = (ushort*)alloc((size_t)N_EDGES * 2 + 512);
  float* dis = (float*)alloc(N_NODES * 4);
  __hip_bfloat16* hW = (__hip_bfloat16*)alloc((size_t)N_NODES * 64 * 2);
  __hip_bfloat16* act = (__hip_bfloat16*)alloc((size_t)N_NODES * 64 * 2);
  float* statsL0 = (float*)alloc(1024 * 4);
  float* statsL1 = (float*)alloc(1024 * 4);
  float* statsL2 = (float*)alloc(1024 * 4);
  float* pooled = (float*)alloc(4096 * 4);

  int nag = (N_NODES + 31) / 32;  // 1563 blocks, 1 node per 8-lane group

  k_zero_small<<<1, 256, 0, stream>>>(ghist, NPART);
  k_hist<<<FILL_BLOCKS, 256, 0, stream>>>(ei + N_EDGES, ghist);
  k_scan196<<<1, 256, 0, stream>>>(ghist, bro, pcur, rowp);
  k_partA<<<FILL_BLOCKS, 256, 0, stream>>>(ei, pcur, tmp);
  k_partB<<<NPART, 256, 0, stream>>>(tmp, bro, dis, rowp, eus);

  // layer 1
  k_gemm<false><<<2048, 256, 0, stream>>>(x, W1, hW, statsL0, nullptr, gamma, beta);
  k_agg_node<<<nag, 256, 0, stream>>>(hW, dis, rowp, eus, b1, act, statsL0);
  // layer 2
  k_gemm<true><<<2048, 256, 0, stream>>>(act, W2, hW, statsL1, statsL0, gamma, beta);
  k_agg_node<<<nag, 256, 0, stream>>>(hW, dis, rowp, eus, b2, act, statsL1);
  // layer 3
  k_gemm<true><<<2048, 256, 0, stream>>>(act, W3, hW, statsL2, statsL1, gamma, beta);
  k_agg_node<<<nag, 256, 0, stream>>>(hW, dis, rowp, eus, b3, act, statsL2);

  k_pool<<<N_GRAPHS, 256, 0, stream>>>(act, statsL2, gamma, beta, pooled);
  k_final<<<1, 256, 0, stream>>>(pooled, l1w, l1b, l2w, l2b, out);
}